// Round 11
// baseline (247.027 us; speedup 1.0000x reference)
//
#include <hip/hip_runtime.h>
#include <cstdint>
#include <cstddef>

typedef __attribute__((ext_vector_type(4))) float f32x4;
typedef __attribute__((ext_vector_type(2))) float f32x2;
typedef __attribute__((ext_vector_type(8))) short short8;
typedef __attribute__((ext_vector_type(8))) __bf16 bf16x8;
typedef unsigned short u16;
typedef unsigned int u32;
typedef __attribute__((ext_vector_type(2))) unsigned int u32x2;
typedef __attribute__((ext_vector_type(4))) unsigned short u16x4;
typedef __attribute__((ext_vector_type(2))) unsigned short u16x2;

#define EPS_RMS 1.1920929e-07f

// ---------- helpers ----------
__device__ __forceinline__ u16 f2bf(float f) {
  union { float f; unsigned u; } v; v.f = f;
  unsigned r = v.u + 0x7FFFu + ((v.u >> 16) & 1u);
  return (u16)(r >> 16);
}
__device__ __forceinline__ float b2f(u16 x) {
  union { unsigned u; float f; } v; v.u = ((unsigned)x) << 16;
  return v.f;
}
__device__ __forceinline__ u32 cvt_pk_bf16(float lo, float hi) {
  u32 r;
  asm("v_cvt_pk_bf16_f32 %0, %1, %2" : "=v"(r) : "v"(lo), "v"(hi));
  return r;
}

template <typename V>
__device__ __forceinline__ auto mfma_try(V a, V b, f32x4 c, int)
    -> decltype(__builtin_amdgcn_mfma_f32_16x16x32_bf16(a, b, c, 0, 0, 0)) {
  return __builtin_amdgcn_mfma_f32_16x16x32_bf16(a, b, c, 0, 0, 0);
}
template <typename V>
__device__ __forceinline__ f32x4 mfma_try(V a, V b, f32x4 c, long) {
  return __builtin_amdgcn_mfma_f32_16x16x32_bf16(
      __builtin_bit_cast(bf16x8, a), __builtin_bit_cast(bf16x8, b), c, 0, 0, 0);
}
__device__ __forceinline__ f32x4 mfma_bf16(short8 a, short8 b, f32x4 c) {
  return mfma_try(a, b, c, 0);
}

__device__ __forceinline__ void load_lds16(u16* lds, const u16* g) {
  auto* gp = reinterpret_cast<const __attribute__((address_space(1))) unsigned int*>(
      reinterpret_cast<uintptr_t>(g));
  auto* lp = reinterpret_cast<__attribute__((address_space(3))) unsigned int*>(
      reinterpret_cast<uintptr_t>(lds));
  __builtin_amdgcn_global_load_lds(gp, lp, 16, 0, 0);
}

__device__ __forceinline__ float fast_exp2(float x) {
  return __builtin_amdgcn_exp2f(x);
}

template <int CTRL>
__device__ __forceinline__ float dpp_step(float v) {
  int t = __builtin_amdgcn_update_dpp(0, __builtin_bit_cast(int, v), CTRL, 0xF, 0xF, true);
  return __builtin_bit_cast(float, t);
}

// ---------- fused conversion kernel (one dispatch for all 5 inputs) ----------
__global__ __launch_bounds__(256) void cvt_all(const float* __restrict__ x,
                                               const float* __restrict__ Wqa,
                                               const float* __restrict__ Wkva,
                                               const float* __restrict__ Wqb,
                                               const float* __restrict__ Wkvb,
                                               const float* __restrict__ Wo,
                                               u16* __restrict__ xb,
                                               u16* __restrict__ wacat,
                                               u16* __restrict__ wqb,
                                               u16* __restrict__ wkvb,
                                               u16* __restrict__ wo) {
  const int blk = blockIdx.x;
  if (blk >= 8192 && blk < 11520) {
    int i = (blk - 8192) * 256 + threadIdx.x;
    int r = i >> 9;
    int c4 = i & 511;
    f32x4 v = {0.f, 0.f, 0.f, 0.f};
    if (r < 1024) v = ((const f32x4*)Wqa)[r * 512 + c4];
    else if (r < 1600) v = ((const f32x4*)Wkva)[(r - 1024) * 512 + c4];
    u16x4 o = {f2bf(v.x), f2bf(v.y), f2bf(v.z), f2bf(v.w)};
    ((u16x4*)wacat)[i] = o;
    return;
  }
  const float* src;
  u16* dst;
  int i;
  if (blk < 8192)       { i = blk * 256 + threadIdx.x;           src = x;    dst = xb;   }
  else if (blk < 14592) { i = (blk - 11520) * 256 + threadIdx.x; src = Wqb;  dst = wqb;  }
  else if (blk < 15104) { i = (blk - 14592) * 256 + threadIdx.x; src = Wkvb; dst = wkvb; }
  else                  { i = (blk - 15104) * 256 + threadIdx.x; src = Wo;   dst = wo;   }
  f32x4 v = ((const f32x4*)src)[i];
  u16x4 o = {f2bf(v.x), f2bf(v.y), f2bf(v.z), f2bf(v.w)};
  ((u16x4*)dst)[i] = o;
}

// ---------- GEMM v1 (proven dbuf 2-phase): C[M,N] = A[M,K] * B[N,K]^T ----------
// Used for G1/G3/G5 (grids 416/256/512 <= 2 blocks/CU: dbuf within-block
// overlap is the right structure there).
template <typename OutT, int EPI>
__global__ __launch_bounds__(256) void gemm_bt(const u16* __restrict__ A,
                                               const u16* __restrict__ B,
                                               OutT* __restrict__ C,
                                               int M, int N, int K, int gx,
                                               const float* __restrict__ fc,
                                               const float* __restrict__ fs,
                                               u16* __restrict__ aux) {
  __shared__ __align__(16) u16 As[2][128 * 64];
  __shared__ __align__(16) u16 Bs[2][128 * 64];
  const int nwg = gridDim.x;
  const int cpx = nwg >> 3;
  const int swz = (blockIdx.x & 7) * cpx + (blockIdx.x >> 3);
  const int by = swz / gx, bxx = swz - by * gx;
  const int tid = threadIdx.x;
  const int lane = tid & 63, w = tid >> 6;
  const int wr = w >> 1, wc = w & 1;
  const int l16 = lane & 15, lg = lane >> 4;
  const int row0 = by * 128, col0 = bxx * 128;

  const u16* Ab = A + (size_t)row0 * K;
  const u16* Bb = B + (size_t)col0 * K;

  f32x4 acc[4][4] = {};

  int soff[4], ldst[4];
#pragma unroll
  for (int j = 0; j < 4; ++j) {
    int c = j * 256 + tid;
    int row = c >> 3;
    int rb = (c & 7) << 4;
    int sb = rb ^ ((row & 7) << 4);
    soff[j] = row * K + (sb >> 1);
    ldst[j] = c * 8;
  }

  // prologue: stage tile 0 into buffer 0
#pragma unroll
  for (int j = 0; j < 4; ++j) load_lds16(As[0] + ldst[j], Ab + soff[j]);
#pragma unroll
  for (int j = 0; j < 4; ++j) load_lds16(Bs[0] + ldst[j], Bb + soff[j]);
  __syncthreads();

  int cur = 0;
  for (int k0 = 0; k0 < K; k0 += 64) {
    if (k0 + 64 < K) {
#pragma unroll
      for (int j = 0; j < 4; ++j) load_lds16(As[cur ^ 1] + ldst[j], Ab + soff[j] + k0 + 64);
#pragma unroll
      for (int j = 0; j < 4; ++j) load_lds16(Bs[cur ^ 1] + ldst[j], Bb + soff[j] + k0 + 64);
    }
    const u16* Ac = As[cur];
    const u16* Bc = Bs[cur];
    short8 a[2][4], bfr[2][4];
#pragma unroll
    for (int mt = 0; mt < 4; ++mt) {
      const int rowA = wr * 64 + mt * 16 + l16;
      const int sw = (rowA & 7) << 4;
#pragma unroll
      for (int kk = 0; kk < 2; ++kk)
        a[kk][mt] = *(const short8*)(Ac + rowA * 64 + (((kk * 64 + lg * 16) ^ sw) >> 1));
    }
#pragma unroll
    for (int nt = 0; nt < 4; ++nt) {
      const int rowB = wc * 64 + nt * 16 + l16;
      const int sw = (rowB & 7) << 4;
#pragma unroll
      for (int kk = 0; kk < 2; ++kk)
        bfr[kk][nt] = *(const short8*)(Bc + rowB * 64 + (((kk * 64 + lg * 16) ^ sw) >> 1));
    }
#pragma unroll
    for (int kk = 0; kk < 2; ++kk)
#pragma unroll
      for (int mt = 0; mt < 4; ++mt)
#pragma unroll
        for (int nt = 0; nt < 4; ++nt)
          acc[mt][nt] = mfma_bf16(a[kk][mt], bfr[kk][nt], acc[mt][nt]);
    __syncthreads();
    cur ^= 1;
  }

  if constexpr (EPI == 0 || EPI == 1) {
#pragma unroll
    for (int mt = 0; mt < 4; ++mt)
#pragma unroll
      for (int nt = 0; nt < 4; ++nt)
#pragma unroll
        for (int i = 0; i < 4; ++i) {
          int row = row0 + wr * 64 + mt * 16 + lg * 4 + i;
          int col = col0 + wc * 64 + nt * 16 + l16;
          if constexpr (EPI == 0)
            C[(size_t)row * N + col] = acc[mt][nt][i];
          else
            C[(size_t)row * N + col] = f2bf(acc[mt][nt][i]);
        }
  } else if constexpr (EPI == 2) {
    const float qscale = 0.07216878364870322f * 1.4426950408889634f;
#pragma unroll
    for (int mt = 0; mt < 4; ++mt)
#pragma unroll
      for (int nt = 0; nt < 4; ++nt) {
        int col = col0 + wc * 64 + nt * 16 + l16;
        int hh = ((col >> 6) * 43) >> 7;   // col/192
        int cin = col - hh * 192;
        int m = (cin - 128) >> 1;
#pragma unroll
        for (int i = 0; i < 4; ++i) {
          int row = row0 + wr * 64 + mt * 16 + lg * 4 + i;
          int bb = row >> 11, ss = row & 2047;
          float v = acc[mt][nt][i];
          float pv = dpp_step<0xB1>(v);  // pair partner (l16^1)
          float val = v;
          if (cin >= 128) {
            float c = fc[ss * 32 + m], sn = fs[ss * 32 + m];
            val = ((l16 & 1) == 0) ? (v * c - pv * sn) : (pv * sn + v * c);
          }
          ((u16*)C)[((size_t)((bb * 16 + hh) * 2048 + ss)) * 192 + cin] = f2bf(val * qscale);
        }
      }
  } else {
#pragma unroll
    for (int mt = 0; mt < 4; ++mt)
#pragma unroll
      for (int nt = 0; nt < 4; ++nt) {
        int col = col0 + wc * 64 + nt * 16 + l16;
        int nn = col >> 8, cin = col & 255;
        int rowb = row0 + wr * 64 + mt * 16 + lg * 4;
        int bb = rowb >> 11, ss0 = rowb & 2047;
        if (cin < 128) {
#pragma unroll
          for (int i = 0; i < 4; ++i)
            ((u16*)C)[((size_t)((bb * 4 + nn) * 2048 + ss0 + i)) * 192 + cin] =
                f2bf(acc[mt][nt][i]);
        } else {
          int dv = cin - 128;
          u16x4 o = {f2bf(acc[mt][nt][0]), f2bf(acc[mt][nt][1]),
                     f2bf(acc[mt][nt][2]), f2bf(acc[mt][nt][3])};
          *(u16x4*)(aux + ((size_t)((bb * 4 + nn) * 128 + dv)) * 2048 + ss0) = o;
        }
      }
  }
}

// ---------- GEMM v2 (m97 single-buffer, 2 barriers/K-step) ----------
// 32 KB LDS -> ~3 blocks/CU. Catalog: this exact structure (128^2 tile,
// global_load_lds w16, pre-swizzled source, 2-barrier) = 874-912 TF; the
// barrier-drain stall is absorbed by cross-block overlap (m114), which
// needs >=3 resident blocks. Only G2 (768 wgs = 3x256) can feed that.
template <typename OutT, int EPI>
__global__ __launch_bounds__(256) void gemm_sb(const u16* __restrict__ A,
                                               const u16* __restrict__ B,
                                               OutT* __restrict__ C,
                                               int M, int N, int K, int gx,
                                               const float* __restrict__ fc,
                                               const float* __restrict__ fs,
                                               u16* __restrict__ aux) {
  __shared__ __align__(16) u16 As[128 * 64];
  __shared__ __align__(16) u16 Bs[128 * 64];
  const int nwg = gridDim.x;
  const int cpx = nwg >> 3;
  const int swz = (blockIdx.x & 7) * cpx + (blockIdx.x >> 3);
  const int by = swz / gx, bxx = swz - by * gx;
  const int tid = threadIdx.x;
  const int lane = tid & 63, w = tid >> 6;
  const int wr = w >> 1, wc = w & 1;
  const int l16 = lane & 15, lg = lane >> 4;
  const int row0 = by * 128, col0 = bxx * 128;

  const u16* Ab = A + (size_t)row0 * K;
  const u16* Bb = B + (size_t)col0 * K;

  f32x4 acc[4][4] = {};

  int soff[4], ldst[4];
#pragma unroll
  for (int j = 0; j < 4; ++j) {
    int c = j * 256 + tid;
    int row = c >> 3;
    int rb = (c & 7) << 4;
    int sb = rb ^ ((row & 7) << 4);
    soff[j] = row * K + (sb >> 1);
    ldst[j] = c * 8;
  }

  for (int k0 = 0; k0 < K; k0 += 64) {
    __syncthreads();   // barrier 1: all waves done reading previous tile
#pragma unroll
    for (int j = 0; j < 4; ++j) load_lds16(As + ldst[j], Ab + soff[j] + k0);
#pragma unroll
    for (int j = 0; j < 4; ++j) load_lds16(Bs + ldst[j], Bb + soff[j] + k0);
    __syncthreads();   // barrier 2: compiler drains vmcnt(0) -> staging visible
    short8 a[2][4], bfr[2][4];
#pragma unroll
    for (int mt = 0; mt < 4; ++mt) {
      const int rowA = wr * 64 + mt * 16 + l16;
      const int sw = (rowA & 7) << 4;
#pragma unroll
      for (int kk = 0; kk < 2; ++kk)
        a[kk][mt] = *(const short8*)(As + rowA * 64 + (((kk * 64 + lg * 16) ^ sw) >> 1));
    }
#pragma unroll
    for (int nt = 0; nt < 4; ++nt) {
      const int rowB = wc * 64 + nt * 16 + l16;
      const int sw = (rowB & 7) << 4;
#pragma unroll
      for (int kk = 0; kk < 2; ++kk)
        bfr[kk][nt] = *(const short8*)(Bs + rowB * 64 + (((kk * 64 + lg * 16) ^ sw) >> 1));
    }
#pragma unroll
    for (int kk = 0; kk < 2; ++kk)
#pragma unroll
      for (int mt = 0; mt < 4; ++mt)
#pragma unroll
        for (int nt = 0; nt < 4; ++nt)
          acc[mt][nt] = mfma_bf16(a[kk][mt], bfr[kk][nt], acc[mt][nt]);
  }

  if constexpr (EPI == 0 || EPI == 1) {
#pragma unroll
    for (int mt = 0; mt < 4; ++mt)
#pragma unroll
      for (int nt = 0; nt < 4; ++nt)
#pragma unroll
        for (int i = 0; i < 4; ++i) {
          int row = row0 + wr * 64 + mt * 16 + lg * 4 + i;
          int col = col0 + wc * 64 + nt * 16 + l16;
          if constexpr (EPI == 0)
            C[(size_t)row * N + col] = acc[mt][nt][i];
          else
            C[(size_t)row * N + col] = f2bf(acc[mt][nt][i]);
        }
  } else if constexpr (EPI == 2) {
    const float qscale = 0.07216878364870322f * 1.4426950408889634f;
#pragma unroll
    for (int mt = 0; mt < 4; ++mt)
#pragma unroll
      for (int nt = 0; nt < 4; ++nt) {
        int col = col0 + wc * 64 + nt * 16 + l16;
        int hh = ((col >> 6) * 43) >> 7;   // col/192
        int cin = col - hh * 192;
        int m = (cin - 128) >> 1;
#pragma unroll
        for (int i = 0; i < 4; ++i) {
          int row = row0 + wr * 64 + mt * 16 + lg * 4 + i;
          int bb = row >> 11, ss = row & 2047;
          float v = acc[mt][nt][i];
          float pv = dpp_step<0xB1>(v);  // pair partner (l16^1)
          float val = v;
          if (cin >= 128) {
            float c = fc[ss * 32 + m], sn = fs[ss * 32 + m];
            val = ((l16 & 1) == 0) ? (v * c - pv * sn) : (pv * sn + v * c);
          }
          ((u16*)C)[((size_t)((bb * 16 + hh) * 2048 + ss)) * 192 + cin] = f2bf(val * qscale);
        }
      }
  } else {
#pragma unroll
    for (int mt = 0; mt < 4; ++mt)
#pragma unroll
      for (int nt = 0; nt < 4; ++nt) {
        int col = col0 + wc * 64 + nt * 16 + l16;
        int nn = col >> 8, cin = col & 255;
        int rowb = row0 + wr * 64 + mt * 16 + lg * 4;
        int bb = rowb >> 11, ss0 = rowb & 2047;
        if (cin < 128) {
#pragma unroll
          for (int i = 0; i < 4; ++i)
            ((u16*)C)[((size_t)((bb * 4 + nn) * 2048 + ss0 + i)) * 192 + cin] =
                f2bf(acc[mt][nt][i]);
        } else {
          int dv = cin - 128;
          u16x4 o = {f2bf(acc[mt][nt][0]), f2bf(acc[mt][nt][1]),
                     f2bf(acc[mt][nt][2]), f2bf(acc[mt][nt][3])};
          *(u16x4*)(aux + ((size_t)((bb * 4 + nn) * 128 + dv)) * 2048 + ss0) = o;
        }
      }
  }
}

// ---------- fused RMS norms (bf16 input; writes k-rope cols of Ka directly) ----------
__global__ __launch_bounds__(256) void rms_fused(const u16* __restrict__ c1b,
                                                 const float* __restrict__ fc,
                                                 const float* __restrict__ fs,
                                                 u16* __restrict__ qlat,
                                                 u16* __restrict__ kvlat,
                                                 u16* __restrict__ Ka) {
  __shared__ float smq[4], smk[4];
  int t = blockIdx.x;
  const u16* row = c1b + (size_t)t * 1664;
  u16x4 v4u = ((const u16x4*)row)[threadIdx.x];
  u16x2 v2u = ((const u16x2*)(row + 1024))[threadIdx.x];
  float v4x = b2f(v4u.x), v4y = b2f(v4u.y), v4z = b2f(v4u.z), v4w = b2f(v4u.w);
  float v2x = b2f(v2u.x), v2y = b2f(v2u.y);
  float sq = v4x * v4x + v4y * v4y + v4z * v4z + v4w * v4w;
  float sk = v2x * v2x + v2y * v2y;
#pragma unroll
  for (int off = 32; off; off >>= 1) { sq += __shfl_xor(sq, off); sk += __shfl_xor(sk, off); }
  if ((threadIdx.x & 63) == 0) { smq[threadIdx.x >> 6] = sq; smk[threadIdx.x >> 6] = sk; }
  __syncthreads();
  float rq = rsqrtf((smq[0] + smq[1] + smq[2] + smq[3]) * (1.0f / 1024.0f) + EPS_RMS);
  float rk = rsqrtf((smk[0] + smk[1] + smk[2] + smk[3]) * (1.0f / 512.0f) + EPS_RMS);
  u16x4 oq = {f2bf(v4x * rq), f2bf(v4y * rq), f2bf(v4z * rq), f2bf(v4w * rq)};
  ((u16x4*)(qlat + (size_t)t * 1024))[threadIdx.x] = oq;
  u16x2 ok = {f2bf(v2x * rk), f2bf(v2y * rk)};
  ((u16x2*)(kvlat + (size_t)t * 512))[threadIdx.x] = ok;
  if (threadIdx.x < 32) {
    int bb = t >> 11, s = t & 2047;
    int m = threadIdx.x;
    float x0 = b2f(row[1536 + 2 * m]), x1 = b2f(row[1537 + 2 * m]);
    float c = fc[s * 32 + m], sn = fs[s * 32 + m];
    u16 r0 = f2bf(x0 * c - x1 * sn);
    u16 r1 = f2bf(x0 * sn + x1 * c);
#pragma unroll
    for (int nn = 0; nn < 4; ++nn) {
      size_t base = ((size_t)((bb * 4 + nn) * 2048 + s)) * 192 + 128;
      Ka[base + 2 * m] = r0;
      Ka[base + 2 * m + 1] = r1;
    }
  }
}

// ---------- flash attention v10 (proven best: 80.2 us, 2 blocks/CU) ----------
__global__ __launch_bounds__(256, 2) void attn_kernel(const u16* __restrict__ Qa,
                                                      const u16* __restrict__ Ka,
                                                      const u16* __restrict__ VTp,
                                                      u16* __restrict__ Ob) {
  __shared__ __align__(16) u16 Ks[64 * 192];
  __shared__ __align__(16) u16 Vs[128 * 64];
  __shared__ __align__(16) u32 Ppk[4][32][36];
  const int gid = blockIdx.x;
  const int bx = (gid < 256) ? (15 - (gid >> 5)) : ((gid - 256) >> 5);
  const int hb = gid & 31;
  const int b = hb >> 4;
  const int h = hb & 15;
  const int n = h >> 2;
  const int tid = threadIdx.x;
  const int lane = tid & 63;
  const int w = tid >> 6;
  const int l16 = lane & 15;
  const int lg = lane >> 4;

  const u16* Qp = Qa + ((size_t)((b * 16 + h) * 2048 + bx * 128 + w * 32)) * 192;
  const u16* Kp = Ka + ((size_t)((b * 4 + n) * 2048)) * 192;
  const u16* Vp = VTp + ((size_t)((b * 4 + n) * 128)) * 2048;

  int oK[6];
#pragma unroll
  for (int j = 0; j < 6; ++j) {
    int c = j * 256 + tid;
    int row = (c * 2731) >> 16;
    int rb = (c - row * 24) << 4;
    int sb = rb ^ ((row & 7) << 4);
    oK[j] = row * 192 + (sb >> 1);
  }
  int oV[4];
#pragma unroll
  for (int j = 0; j < 4; ++j) {
    int c = j * 256 + tid;
    int row = c >> 3;
    int rb = (c & 7) << 4;
    int sb = rb ^ ((row & 7) << 4);
    oV[j] = row * 2048 + (sb >> 1);
  }

  short8 qf[2][6];
#pragma unroll
  for (int g = 0; g < 2; ++g)
#pragma unroll
    for (int kc = 0; kc < 6; ++kc)
      qf[g][kc] = *(const short8*)(Qp + (size_t)(g * 16 + l16) * 192 + kc * 32 + lg * 8);

  float mrow[2], lrow[2];
  f32x4 oacc[2][8];
#pragma unroll
  for (int g = 0; g < 2; ++g) { mrow[g] = -1e30f; lrow[g] = 0.f; }
#pragma unroll
  for (int g = 0; g < 2; ++g)
#pragma unroll
    for (int vb = 0; vb < 8; ++vb) oacc[g][vb] = (f32x4){0.f, 0.f, 0.f, 0.f};

  const int wrow = bx * 128 + w * 32;
  const int NT = 2 * bx + 2;

  f32x4 kreg[6], vreg[4];
#pragma unroll
  for (int j = 0; j < 6; ++j) kreg[j] = *(const f32x4*)(Kp + oK[j]);
#pragma unroll
  for (int j = 0; j < 4; ++j) vreg[j] = *(const f32x4*)(Vp + oV[j]);

  for (int kt = 0; kt < NT; ++kt) {
    const int kb = kt * 64;
    __syncthreads();
#pragma unroll
    for (int j = 0; j < 6; ++j) *(f32x4*)(Ks + (j * 256 + tid) * 8) = kreg[j];
#pragma unroll
    for (int j = 0; j < 4; ++j) *(f32x4*)(Vs + (j * 256 + tid) * 8) = vreg[j];
    __syncthreads();
    if (kt + 1 < NT) {
      const int kb2 = kb + 64;
#pragma unroll
      for (int j = 0; j < 6; ++j)
        kreg[j] = *(const f32x4*)(Kp + oK[j] + (size_t)kb2 * 192);
#pragma unroll
      for (int j = 0; j < 4; ++j)
        vreg[j] = *(const f32x4*)(Vp + oV[j] + kb2);
    }
    if (kb > wrow + 31) continue;

    f32x4 sc[2][4];
#pragma unroll
    for (int g = 0; g < 2; ++g)
#pragma unroll
      for (int kn = 0; kn < 4; ++kn) sc[g][kn] = (f32x4){0.f, 0.f, 0.f, 0.f};
    __builtin_amdgcn_s_setprio(1);
#pragma unroll
    for (int kn = 0; kn < 4; ++kn) {
      const int rk = kn * 16 + l16;
      const u16* kbase = Ks + rk * 192;
      const int sw = (rk & 7) << 4;
#pragma unroll
      for (int kc = 0; kc < 6; ++kc) {
        short8 kf = *(const short8*)(kbase + (((kc * 64 + lg * 16) ^ sw) >> 1));
        sc[0][kn] = mfma_bf16(kf, qf[0][kc], sc[0][kn]);
        sc[1][kn] = mfma_bf16(kf, qf[1][kc], sc[1][kn]);
      }
    }
    __builtin_amdgcn_s_setprio(0);
    if (kb + 63 > wrow) {
#pragma unroll
      for (int g = 0; g < 2; ++g) {
        const int qabs = wrow + g * 16 + l16;
#pragma unroll
        for (int kn = 0; kn < 4; ++kn)
#pragma unroll
          for (int i = 0; i < 4; ++i)
            if (kb + kn * 16 + lg * 4 + i > qabs) sc[g][kn][i] = -1e30f;
      }
    }
    float pmax[2];
    int need = 0;
#pragma unroll
    for (int g = 0; g < 2; ++g) {
      float v = -1e30f;
#pragma unroll
      for (int kn = 0; kn < 4; ++kn)
        v = fmaxf(v, fmaxf(fmaxf(sc[g][kn][0], sc[g][kn][1]),
                           fmaxf(sc[g][kn][2], sc[g][kn][3])));
      v = fmaxf(v, __shfl_xor(v, 16));
      v = fmaxf(v, __shfl_xor(v, 32));
      pmax[g] = v;
      need |= (v > mrow[g] + 8.0f) ? 1 : 0;
    }
    if (__any(need)) {
#pragma unroll
      for (int g = 0; g < 2; ++g) {
        float mn = fmaxf(mrow[g], pmax[g]);
        float al = fast_exp2(mrow[g] - mn);
        mrow[g] = mn;
        lrow[g] *= al;
#pragma unroll
        for (int i = 0; i < 4; ++i) {
          float alq = __shfl(al, lg * 4 + i);
#pragma unroll
          for (int vb = 0; vb < 8; ++vb) oacc[g][vb][i] *= alq;
        }
      }
    }
#pragma unroll
    for (int g = 0; g < 2; ++g) {
      float rs = 0.f;
#pragma unroll
      for (int kn = 0; kn < 4; ++kn)
#pragma unroll
        for (int i = 0; i < 4; ++i) {
          float p = fast_exp2(sc[g][kn][i] - mrow[g]);
          sc[g][kn][i] = p;
          rs += p;
        }
      rs += __shfl_xor(rs, 16);
      rs += __shfl_xor(rs, 32);
      lrow[g] += rs;
    }
#pragma unroll
    for (int g = 0; g < 2; ++g) {
      const int r = g * 16 + l16;
#pragma unroll
      for (int kn = 0; kn < 4; ++kn) {
        u32x2 pk = {cvt_pk_bf16(sc[g][kn][0], sc[g][kn][1]),
                    cvt_pk_bf16(sc[g][kn][2], sc[g][kn][3])};
        *(u32x2*)&Ppk[w][r][kn * 8 + 2 * lg] = pk;
      }
    }
    short8 pa[2][2];
#pragma unroll
    for (int g = 0; g < 2; ++g) {
      const int r = g * 16 + l16;
      pa[g][0] = *(const short8*)&Ppk[w][r][lg * 4];
      pa[g][1] = *(const short8*)&Ppk[w][r][16 + lg * 4];
    }
    __builtin_amdgcn_s_setprio(1);
#pragma unroll
    for (int vb = 0; vb < 8; ++vb) {
      const int rv = vb * 16 + l16;
      const u16* vbase = Vs + rv * 64;
      const int swv = (rv & 7) << 4;
      short8 v0 = *(const short8*)(vbase + (((lg * 16) ^ swv) >> 1));
      short8 v1 = *(const short8*)(vbase + (((64 + lg * 16) ^ swv) >> 1));
      oacc[0][vb] = mfma_bf16(pa[0][0], v0, oacc[0][vb]);
      oacc[1][vb] = mfma_bf16(pa[1][0], v0, oacc[1][vb]);
      oacc[0][vb] = mfma_bf16(pa[0][1], v1, oacc[0][vb]);
      oacc[1][vb] = mfma_bf16(pa[1][1], v1, oacc[1][vb]);
    }
    __builtin_amdgcn_s_setprio(0);
  }
#pragma unroll
  for (int g = 0; g < 2; ++g) {
    float inv = 1.0f / lrow[g];
#pragma unroll
    for (int i = 0; i < 4; ++i) {
      float invq = __shfl(inv, lg * 4 + i);
      int srow = wrow + g * 16 + lg * 4 + i;
      size_t base = ((size_t)(b * 2048 + srow)) * 2048 + h * 128;
#pragma unroll
      for (int vb = 0; vb < 8; ++vb)
        Ob[base + vb * 16 + l16] = f2bf(oacc[g][vb][i] * invq);
    }
  }
}

// ---------- launch ----------
extern "C" void kernel_launch(void* const* d_in, const int* in_sizes, int n_in,
                              void* d_out, int out_size, void* d_ws, size_t ws_size,
                              hipStream_t stream) {
  const float* x = (const float*)d_in[0];
  const float* fc = (const float*)d_in[1];
  const float* fs = (const float*)d_in[2];
  const float* Wqa = (const float*)d_in[3];
  const float* Wqb = (const float*)d_in[4];
  const float* Wkva = (const float*)d_in[5];
  const float* Wkvb = (const float*)d_in[6];
  const float* Wo = (const float*)d_in[7];
  float* out = (float*)d_out;

  char* ws = (char*)d_ws;
  u16* xb    = (u16*)(ws + 0);            // 4096x2048 bf16
  u16* wacat = (u16*)(ws + 16777216);     // 1664x2048 bf16
  u16* wqb   = (u16*)(ws + 23592960);     // 3072x1024 bf16
  u16* wkvb  = (u16*)(ws + 29884416);     // 1024x512 bf16
  u16* wo    = (u16*)(ws + 30932992);     // 2048x2048 bf16
  u16* c1b   = (u16*)(ws + 39321600);     // 4096x1664 bf16
  u16* qlat  = (u16*)(ws + 52953088);     // 4096x1024 bf16
  u16* kvlat = (u16*)(ws + 61341696);     // 4096x512 bf16
  u16* obf   = (u16*)(ws + 65536000);     // 4096x2048 bf16
  u16* qattn = (u16*)(ws + 82313216);     // 2x16x2048x192
  u16* kattn = (u16*)(ws + 107479040);    // 2x4x2048x192
  u16* vt    = (u16*)(ws + 113770496);    // 2x4x128x2048
  if (ws_size < 117964800u) return;

  cvt_all<<<19200, 256, 0, stream>>>(x, Wqa, Wkva, Wqb, Wkvb, Wo,
                                     xb, wacat, wqb, wkvb, wo);

  gemm_bt<u16, 1><<<416, 256, 0, stream>>>(xb, wacat, c1b, 4096, 1664, 2048, 13,
                                           nullptr, nullptr, nullptr);
  rms_fused<<<4096, 256, 0, stream>>>(c1b, fc, fs, qlat, kvlat, kattn);
  gemm_sb<u16, 2><<<768, 256, 0, stream>>>(qlat, wqb, qattn, 4096, 3072, 1024, 24,
                                           fc, fs, nullptr);
  gemm_bt<u16, 3><<<256, 256, 0, stream>>>(kvlat, wkvb, kattn, 4096, 1024, 512, 8,
                                           nullptr, nullptr, vt);
  attn_kernel<<<512, 256, 0, stream>>>(qattn, kattn, vt, obf);
  gemm_bt<float, 0><<<512, 256, 0, stream>>>(obf, wo, out, 4096, 2048, 2048, 16,
                                             nullptr, nullptr, nullptr);
}

// Round 12
// 237.621 us; speedup vs baseline: 1.0396x; 1.0396x over previous
//
#include <hip/hip_runtime.h>
#include <cstdint>
#include <cstddef>

typedef __attribute__((ext_vector_type(4))) float f32x4;
typedef __attribute__((ext_vector_type(2))) float f32x2;
typedef __attribute__((ext_vector_type(8))) short short8;
typedef __attribute__((ext_vector_type(8))) __bf16 bf16x8;
typedef unsigned short u16;
typedef unsigned int u32;
typedef __attribute__((ext_vector_type(2))) unsigned int u32x2;
typedef __attribute__((ext_vector_type(4))) unsigned short u16x4;
typedef __attribute__((ext_vector_type(2))) unsigned short u16x2;

#define EPS_RMS 1.1920929e-07f

// ---------- helpers ----------
__device__ __forceinline__ u16 f2bf(float f) {
  union { float f; unsigned u; } v; v.f = f;
  unsigned r = v.u + 0x7FFFu + ((v.u >> 16) & 1u);
  return (u16)(r >> 16);
}
__device__ __forceinline__ float b2f(u16 x) {
  union { unsigned u; float f; } v; v.u = ((unsigned)x) << 16;
  return v.f;
}
__device__ __forceinline__ u32 cvt_pk_bf16(float lo, float hi) {
  u32 r;
  asm("v_cvt_pk_bf16_f32 %0, %1, %2" : "=v"(r) : "v"(lo), "v"(hi));
  return r;
}

template <typename V>
__device__ __forceinline__ auto mfma_try(V a, V b, f32x4 c, int)
    -> decltype(__builtin_amdgcn_mfma_f32_16x16x32_bf16(a, b, c, 0, 0, 0)) {
  return __builtin_amdgcn_mfma_f32_16x16x32_bf16(a, b, c, 0, 0, 0);
}
template <typename V>
__device__ __forceinline__ f32x4 mfma_try(V a, V b, f32x4 c, long) {
  return __builtin_amdgcn_mfma_f32_16x16x32_bf16(
      __builtin_bit_cast(bf16x8, a), __builtin_bit_cast(bf16x8, b), c, 0, 0, 0);
}
__device__ __forceinline__ f32x4 mfma_bf16(short8 a, short8 b, f32x4 c) {
  return mfma_try(a, b, c, 0);
}

__device__ __forceinline__ void load_lds16(u16* lds, const u16* g) {
  auto* gp = reinterpret_cast<const __attribute__((address_space(1))) unsigned int*>(
      reinterpret_cast<uintptr_t>(g));
  auto* lp = reinterpret_cast<__attribute__((address_space(3))) unsigned int*>(
      reinterpret_cast<uintptr_t>(lds));
  __builtin_amdgcn_global_load_lds(gp, lp, 16, 0, 0);
}

__device__ __forceinline__ float fast_exp2(float x) {
  return __builtin_amdgcn_exp2f(x);
}

template <int CTRL>
__device__ __forceinline__ float dpp_step(float v) {
  int t = __builtin_amdgcn_update_dpp(0, __builtin_bit_cast(int, v), CTRL, 0xF, 0xF, true);
  return __builtin_bit_cast(float, t);
}

// ---------- fused conversion kernel (one dispatch for all 5 inputs) ----------
// Block ranges (all exactly 256-thread aligned):
//   [0,8192)      x     -> xb      (2097152 quads)
//   [8192,11520)  wacat (Wqa/Wkva concat + zero pad, 851968 quads)
//   [11520,14592) Wqb   -> wqb     (786432 quads)
//   [14592,15104) Wkvb  -> wkvb    (131072 quads)
//   [15104,19200) Wo    -> wo      (1048576 quads)
__global__ __launch_bounds__(256) void cvt_all(const float* __restrict__ x,
                                               const float* __restrict__ Wqa,
                                               const float* __restrict__ Wkva,
                                               const float* __restrict__ Wqb,
                                               const float* __restrict__ Wkvb,
                                               const float* __restrict__ Wo,
                                               u16* __restrict__ xb,
                                               u16* __restrict__ wacat,
                                               u16* __restrict__ wqb,
                                               u16* __restrict__ wkvb,
                                               u16* __restrict__ wo) {
  const int blk = blockIdx.x;
  if (blk >= 8192 && blk < 11520) {
    int i = (blk - 8192) * 256 + threadIdx.x;
    int r = i >> 9;
    int c4 = i & 511;
    f32x4 v = {0.f, 0.f, 0.f, 0.f};
    if (r < 1024) v = ((const f32x4*)Wqa)[r * 512 + c4];
    else if (r < 1600) v = ((const f32x4*)Wkva)[(r - 1024) * 512 + c4];
    u16x4 o = {f2bf(v.x), f2bf(v.y), f2bf(v.z), f2bf(v.w)};
    ((u16x4*)wacat)[i] = o;
    return;
  }
  const float* src;
  u16* dst;
  int i;
  if (blk < 8192)       { i = blk * 256 + threadIdx.x;           src = x;    dst = xb;   }
  else if (blk < 14592) { i = (blk - 11520) * 256 + threadIdx.x; src = Wqb;  dst = wqb;  }
  else if (blk < 15104) { i = (blk - 14592) * 256 + threadIdx.x; src = Wkvb; dst = wkvb; }
  else                  { i = (blk - 15104) * 256 + threadIdx.x; src = Wo;   dst = wo;   }
  f32x4 v = ((const f32x4*)src)[i];
  u16x4 o = {f2bf(v.x), f2bf(v.y), f2bf(v.z), f2bf(v.w)};
  ((u16x4*)dst)[i] = o;
}

// ---------- GEMM (proven dbuf 2-phase): C[M,N] = A[M,K] * B[N,K]^T ----------
// BK=64, T2 XOR swizzle, T1 XCD swizzle, minimum-2-phase double buffer.
// Session R11: single-buffer m97 variant at 3 blocks/CU is 8.5us WORSE at
// our shapes (K small -> dbuf within-block overlap wins). Keep dbuf for all.
// EPI: 0=f32 out, 1=bf16 out, 2=fused Q rope->Qa, 3=fused KV split->Ka/VT.
template <typename OutT, int EPI>
__global__ __launch_bounds__(256) void gemm_bt(const u16* __restrict__ A,
                                               const u16* __restrict__ B,
                                               OutT* __restrict__ C,
                                               int M, int N, int K, int gx,
                                               const float* __restrict__ fc,
                                               const float* __restrict__ fs,
                                               u16* __restrict__ aux) {
  __shared__ __align__(16) u16 As[2][128 * 64];
  __shared__ __align__(16) u16 Bs[2][128 * 64];
  const int nwg = gridDim.x;
  const int cpx = nwg >> 3;
  const int swz = (blockIdx.x & 7) * cpx + (blockIdx.x >> 3);
  const int by = swz / gx, bxx = swz - by * gx;
  const int tid = threadIdx.x;
  const int lane = tid & 63, w = tid >> 6;
  const int wr = w >> 1, wc = w & 1;
  const int l16 = lane & 15, lg = lane >> 4;
  const int row0 = by * 128, col0 = bxx * 128;

  const u16* Ab = A + (size_t)row0 * K;
  const u16* Bb = B + (size_t)col0 * K;

  f32x4 acc[4][4] = {};

  int soff[4], ldst[4];
#pragma unroll
  for (int j = 0; j < 4; ++j) {
    int c = j * 256 + tid;
    int row = c >> 3;
    int rb = (c & 7) << 4;
    int sb = rb ^ ((row & 7) << 4);
    soff[j] = row * K + (sb >> 1);
    ldst[j] = c * 8;
  }

  // prologue: stage tile 0 into buffer 0
#pragma unroll
  for (int j = 0; j < 4; ++j) load_lds16(As[0] + ldst[j], Ab + soff[j]);
#pragma unroll
  for (int j = 0; j < 4; ++j) load_lds16(Bs[0] + ldst[j], Bb + soff[j]);
  __syncthreads();

  int cur = 0;
  for (int k0 = 0; k0 < K; k0 += 64) {
    if (k0 + 64 < K) {
#pragma unroll
      for (int j = 0; j < 4; ++j) load_lds16(As[cur ^ 1] + ldst[j], Ab + soff[j] + k0 + 64);
#pragma unroll
      for (int j = 0; j < 4; ++j) load_lds16(Bs[cur ^ 1] + ldst[j], Bb + soff[j] + k0 + 64);
    }
    const u16* Ac = As[cur];
    const u16* Bc = Bs[cur];
    short8 a[2][4], bfr[2][4];
#pragma unroll
    for (int mt = 0; mt < 4; ++mt) {
      const int rowA = wr * 64 + mt * 16 + l16;
      const int sw = (rowA & 7) << 4;
#pragma unroll
      for (int kk = 0; kk < 2; ++kk)
        a[kk][mt] = *(const short8*)(Ac + rowA * 64 + (((kk * 64 + lg * 16) ^ sw) >> 1));
    }
#pragma unroll
    for (int nt = 0; nt < 4; ++nt) {
      const int rowB = wc * 64 + nt * 16 + l16;
      const int sw = (rowB & 7) << 4;
#pragma unroll
      for (int kk = 0; kk < 2; ++kk)
        bfr[kk][nt] = *(const short8*)(Bc + rowB * 64 + (((kk * 64 + lg * 16) ^ sw) >> 1));
    }
#pragma unroll
    for (int kk = 0; kk < 2; ++kk)
#pragma unroll
      for (int mt = 0; mt < 4; ++mt)
#pragma unroll
        for (int nt = 0; nt < 4; ++nt)
          acc[mt][nt] = mfma_bf16(a[kk][mt], bfr[kk][nt], acc[mt][nt]);
    __syncthreads();
    cur ^= 1;
  }

  if constexpr (EPI == 0 || EPI == 1) {
#pragma unroll
    for (int mt = 0; mt < 4; ++mt)
#pragma unroll
      for (int nt = 0; nt < 4; ++nt)
#pragma unroll
        for (int i = 0; i < 4; ++i) {
          int row = row0 + wr * 64 + mt * 16 + lg * 4 + i;
          int col = col0 + wc * 64 + nt * 16 + l16;
          if constexpr (EPI == 0)
            C[(size_t)row * N + col] = acc[mt][nt][i];
          else
            C[(size_t)row * N + col] = f2bf(acc[mt][nt][i]);
        }
  } else if constexpr (EPI == 2) {
    const float qscale = 0.07216878364870322f * 1.4426950408889634f;
#pragma unroll
    for (int mt = 0; mt < 4; ++mt)
#pragma unroll
      for (int nt = 0; nt < 4; ++nt) {
        int col = col0 + wc * 64 + nt * 16 + l16;
        int hh = ((col >> 6) * 43) >> 7;   // col/192
        int cin = col - hh * 192;
        int m = (cin - 128) >> 1;
#pragma unroll
        for (int i = 0; i < 4; ++i) {
          int row = row0 + wr * 64 + mt * 16 + lg * 4 + i;
          int bb = row >> 11, ss = row & 2047;
          float v = acc[mt][nt][i];
          float pv = dpp_step<0xB1>(v);  // pair partner (l16^1)
          float val = v;
          if (cin >= 128) {
            float c = fc[ss * 32 + m], sn = fs[ss * 32 + m];
            val = ((l16 & 1) == 0) ? (v * c - pv * sn) : (pv * sn + v * c);
          }
          ((u16*)C)[((size_t)((bb * 16 + hh) * 2048 + ss)) * 192 + cin] = f2bf(val * qscale);
        }
      }
  } else {
#pragma unroll
    for (int mt = 0; mt < 4; ++mt)
#pragma unroll
      for (int nt = 0; nt < 4; ++nt) {
        int col = col0 + wc * 64 + nt * 16 + l16;
        int nn = col >> 8, cin = col & 255;
        int rowb = row0 + wr * 64 + mt * 16 + lg * 4;
        int bb = rowb >> 11, ss0 = rowb & 2047;
        if (cin < 128) {
#pragma unroll
          for (int i = 0; i < 4; ++i)
            ((u16*)C)[((size_t)((bb * 4 + nn) * 2048 + ss0 + i)) * 192 + cin] =
                f2bf(acc[mt][nt][i]);
        } else {
          int dv = cin - 128;
          u16x4 o = {f2bf(acc[mt][nt][0]), f2bf(acc[mt][nt][1]),
                     f2bf(acc[mt][nt][2]), f2bf(acc[mt][nt][3])};
          *(u16x4*)(aux + ((size_t)((bb * 4 + nn) * 128 + dv)) * 2048 + ss0) = o;
        }
      }
  }
}

// ---------- fused RMS norms (bf16 input; writes k-rope cols of Ka directly) ----------
__global__ __launch_bounds__(256) void rms_fused(const u16* __restrict__ c1b,
                                                 const float* __restrict__ fc,
                                                 const float* __restrict__ fs,
                                                 u16* __restrict__ qlat,
                                                 u16* __restrict__ kvlat,
                                                 u16* __restrict__ Ka) {
  __shared__ float smq[4], smk[4];
  int t = blockIdx.x;
  const u16* row = c1b + (size_t)t * 1664;
  u16x4 v4u = ((const u16x4*)row)[threadIdx.x];
  u16x2 v2u = ((const u16x2*)(row + 1024))[threadIdx.x];
  float v4x = b2f(v4u.x), v4y = b2f(v4u.y), v4z = b2f(v4u.z), v4w = b2f(v4u.w);
  float v2x = b2f(v2u.x), v2y = b2f(v2u.y);
  float sq = v4x * v4x + v4y * v4y + v4z * v4z + v4w * v4w;
  float sk = v2x * v2x + v2y * v2y;
#pragma unroll
  for (int off = 32; off; off >>= 1) { sq += __shfl_xor(sq, off); sk += __shfl_xor(sk, off); }
  if ((threadIdx.x & 63) == 0) { smq[threadIdx.x >> 6] = sq; smk[threadIdx.x >> 6] = sk; }
  __syncthreads();
  float rq = rsqrtf((smq[0] + smq[1] + smq[2] + smq[3]) * (1.0f / 1024.0f) + EPS_RMS);
  float rk = rsqrtf((smk[0] + smk[1] + smk[2] + smk[3]) * (1.0f / 512.0f) + EPS_RMS);
  u16x4 oq = {f2bf(v4x * rq), f2bf(v4y * rq), f2bf(v4z * rq), f2bf(v4w * rq)};
  ((u16x4*)(qlat + (size_t)t * 1024))[threadIdx.x] = oq;
  u16x2 ok = {f2bf(v2x * rk), f2bf(v2y * rk)};
  ((u16x2*)(kvlat + (size_t)t * 512))[threadIdx.x] = ok;
  if (threadIdx.x < 32) {
    int bb = t >> 11, s = t & 2047;
    int m = threadIdx.x;
    float x0 = b2f(row[1536 + 2 * m]), x1 = b2f(row[1537 + 2 * m]);
    float c = fc[s * 32 + m], sn = fs[s * 32 + m];
    u16 r0 = f2bf(x0 * c - x1 * sn);
    u16 r1 = f2bf(x0 * sn + x1 * c);
#pragma unroll
    for (int nn = 0; nn < 4; ++nn) {
      size_t base = ((size_t)((bb * 4 + nn) * 2048 + s)) * 192 + 128;
      Ka[base + 2 * m] = r0;
      Ka[base + 2 * m + 1] = r1;
    }
  }
}

// ---------- flash attention v10 (proven best: 80.2 us, 2 blocks/CU) ----------
// Session evidence (R1-R11): pipe-mix saturated at 2 blocks/CU (MFMA 22 +
// VALU 22 + LDS ~37 = ~81% issue budget). Occupancy levers null (R4/R7),
// setprio null (R8), 1-block dbuf -34% (R9). Structure floor.
__global__ __launch_bounds__(256, 2) void attn_kernel(const u16* __restrict__ Qa,
                                                      const u16* __restrict__ Ka,
                                                      const u16* __restrict__ VTp,
                                                      u16* __restrict__ Ob) {
  __shared__ __align__(16) u16 Ks[64 * 192];
  __shared__ __align__(16) u16 Vs[128 * 64];
  __shared__ __align__(16) u32 Ppk[4][32][36];
  const int gid = blockIdx.x;
  const int bx = (gid < 256) ? (15 - (gid >> 5)) : ((gid - 256) >> 5);
  const int hb = gid & 31;
  const int b = hb >> 4;
  const int h = hb & 15;
  const int n = h >> 2;
  const int tid = threadIdx.x;
  const int lane = tid & 63;
  const int w = tid >> 6;
  const int l16 = lane & 15;
  const int lg = lane >> 4;

  const u16* Qp = Qa + ((size_t)((b * 16 + h) * 2048 + bx * 128 + w * 32)) * 192;
  const u16* Kp = Ka + ((size_t)((b * 4 + n) * 2048)) * 192;
  const u16* Vp = VTp + ((size_t)((b * 4 + n) * 128)) * 2048;

  int oK[6];
#pragma unroll
  for (int j = 0; j < 6; ++j) {
    int c = j * 256 + tid;
    int row = (c * 2731) >> 16;
    int rb = (c - row * 24) << 4;
    int sb = rb ^ ((row & 7) << 4);
    oK[j] = row * 192 + (sb >> 1);
  }
  int oV[4];
#pragma unroll
  for (int j = 0; j < 4; ++j) {
    int c = j * 256 + tid;
    int row = c >> 3;
    int rb = (c & 7) << 4;
    int sb = rb ^ ((row & 7) << 4);
    oV[j] = row * 2048 + (sb >> 1);
  }

  short8 qf[2][6];
#pragma unroll
  for (int g = 0; g < 2; ++g)
#pragma unroll
    for (int kc = 0; kc < 6; ++kc)
      qf[g][kc] = *(const short8*)(Qp + (size_t)(g * 16 + l16) * 192 + kc * 32 + lg * 8);

  float mrow[2], lrow[2];
  f32x4 oacc[2][8];
#pragma unroll
  for (int g = 0; g < 2; ++g) { mrow[g] = -1e30f; lrow[g] = 0.f; }
#pragma unroll
  for (int g = 0; g < 2; ++g)
#pragma unroll
    for (int vb = 0; vb < 8; ++vb) oacc[g][vb] = (f32x4){0.f, 0.f, 0.f, 0.f};

  const int wrow = bx * 128 + w * 32;
  const int NT = 2 * bx + 2;

  f32x4 kreg[6], vreg[4];
#pragma unroll
  for (int j = 0; j < 6; ++j) kreg[j] = *(const f32x4*)(Kp + oK[j]);
#pragma unroll
  for (int j = 0; j < 4; ++j) vreg[j] = *(const f32x4*)(Vp + oV[j]);

  for (int kt = 0; kt < NT; ++kt) {
    const int kb = kt * 64;
    __syncthreads();
#pragma unroll
    for (int j = 0; j < 6; ++j) *(f32x4*)(Ks + (j * 256 + tid) * 8) = kreg[j];
#pragma unroll
    for (int j = 0; j < 4; ++j) *(f32x4*)(Vs + (j * 256 + tid) * 8) = vreg[j];
    __syncthreads();
    if (kt + 1 < NT) {
      const int kb2 = kb + 64;
#pragma unroll
      for (int j = 0; j < 6; ++j)
        kreg[j] = *(const f32x4*)(Kp + oK[j] + (size_t)kb2 * 192);
#pragma unroll
      for (int j = 0; j < 4; ++j)
        vreg[j] = *(const f32x4*)(Vp + oV[j] + kb2);
    }
    if (kb > wrow + 31) continue;

    f32x4 sc[2][4];
#pragma unroll
    for (int g = 0; g < 2; ++g)
#pragma unroll
      for (int kn = 0; kn < 4; ++kn) sc[g][kn] = (f32x4){0.f, 0.f, 0.f, 0.f};
    __builtin_amdgcn_s_setprio(1);
#pragma unroll
    for (int kn = 0; kn < 4; ++kn) {
      const int rk = kn * 16 + l16;
      const u16* kbase = Ks + rk * 192;
      const int sw = (rk & 7) << 4;
#pragma unroll
      for (int kc = 0; kc < 6; ++kc) {
        short8 kf = *(const short8*)(kbase + (((kc * 64 + lg * 16) ^ sw) >> 1));
        sc[0][kn] = mfma_bf16(kf, qf[0][kc], sc[0][kn]);
        sc[1][kn] = mfma_bf16(kf, qf[1][kc], sc[1][kn]);
      }
    }
    __builtin_amdgcn_s_setprio(0);
    if (kb + 63 > wrow) {
#pragma unroll
      for (int g = 0; g < 2; ++g) {
        const int qabs = wrow + g * 16 + l16;
#pragma unroll
        for (int kn = 0; kn < 4; ++kn)
#pragma unroll
          for (int i = 0; i < 4; ++i)
            if (kb + kn * 16 + lg * 4 + i > qabs) sc[g][kn][i] = -1e30f;
      }
    }
    float pmax[2];
    int need = 0;
#pragma unroll
    for (int g = 0; g < 2; ++g) {
      float v = -1e30f;
#pragma unroll
      for (int kn = 0; kn < 4; ++kn)
        v = fmaxf(v, fmaxf(fmaxf(sc[g][kn][0], sc[g][kn][1]),
                           fmaxf(sc[g][kn][2], sc[g][kn][3])));
      v = fmaxf(v, __shfl_xor(v, 16));
      v = fmaxf(v, __shfl_xor(v, 32));
      pmax[g] = v;
      need |= (v > mrow[g] + 8.0f) ? 1 : 0;
    }
    if (__any(need)) {
#pragma unroll
      for (int g = 0; g < 2; ++g) {
        float mn = fmaxf(mrow[g], pmax[g]);
        float al = fast_exp2(mrow[g] - mn);
        mrow[g] = mn;
        lrow[g] *= al;
#pragma unroll
        for (int i = 0; i < 4; ++i) {
          float alq = __shfl(al, lg * 4 + i);
#pragma unroll
          for (int vb = 0; vb < 8; ++vb) oacc[g][vb][i] *= alq;
        }
      }
    }
#pragma unroll
    for (int g = 0; g < 2; ++g) {
      float rs = 0.f;
#pragma unroll
      for (int kn = 0; kn < 4; ++kn)
#pragma unroll
        for (int i = 0; i < 4; ++i) {
          float p = fast_exp2(sc[g][kn][i] - mrow[g]);
          sc[g][kn][i] = p;
          rs += p;
        }
      rs += __shfl_xor(rs, 16);
      rs += __shfl_xor(rs, 32);
      lrow[g] += rs;
    }
#pragma unroll
    for (int g = 0; g < 2; ++g) {
      const int r = g * 16 + l16;
#pragma unroll
      for (int kn = 0; kn < 4; ++kn) {
        u32x2 pk = {cvt_pk_bf16(sc[g][kn][0], sc[g][kn][1]),
                    cvt_pk_bf16(sc[g][kn][2], sc[g][kn][3])};
        *(u32x2*)&Ppk[w][r][kn * 8 + 2 * lg] = pk;
      }
    }
    short8 pa[2][2];
#pragma unroll
    for (int g = 0; g < 2; ++g) {
      const int r = g * 16 + l16;
      pa[g][0] = *(const short8*)&Ppk[w][r][lg * 4];
      pa[g][1] = *(const short8*)&Ppk[w][r][16 + lg * 4];
    }
    __builtin_amdgcn_s_setprio(1);
#pragma unroll
    for (int vb = 0; vb < 8; ++vb) {
      const int rv = vb * 16 + l16;
      const u16* vbase = Vs + rv * 64;
      const int swv = (rv & 7) << 4;
      short8 v0 = *(const short8*)(vbase + (((lg * 16) ^ swv) >> 1));
      short8 v1 = *(const short8*)(vbase + (((64 + lg * 16) ^ swv) >> 1));
      oacc[0][vb] = mfma_bf16(pa[0][0], v0, oacc[0][vb]);
      oacc[1][vb] = mfma_bf16(pa[1][0], v0, oacc[1][vb]);
      oacc[0][vb] = mfma_bf16(pa[0][1], v1, oacc[0][vb]);
      oacc[1][vb] = mfma_bf16(pa[1][1], v1, oacc[1][vb]);
    }
    __builtin_amdgcn_s_setprio(0);
  }
#pragma unroll
  for (int g = 0; g < 2; ++g) {
    float inv = 1.0f / lrow[g];
#pragma unroll
    for (int i = 0; i < 4; ++i) {
      float invq = __shfl(inv, lg * 4 + i);
      int srow = wrow + g * 16 + lg * 4 + i;
      size_t base = ((size_t)(b * 2048 + srow)) * 2048 + h * 128;
#pragma unroll
      for (int vb = 0; vb < 8; ++vb)
        Ob[base + vb * 16 + l16] = f2bf(oacc[g][vb][i] * invq);
    }
  }
}

// ---------- launch ----------
extern "C" void kernel_launch(void* const* d_in, const int* in_sizes, int n_in,
                              void* d_out, int out_size, void* d_ws, size_t ws_size,
                              hipStream_t stream) {
  const float* x = (const float*)d_in[0];
  const float* fc = (const float*)d_in[1];
  const float* fs = (const float*)d_in[2];
  const float* Wqa = (const float*)d_in[3];
  const float* Wqb = (const float*)d_in[4];
  const float* Wkva = (const float*)d_in[5];
  const float* Wkvb = (const float*)d_in[6];
  const float* Wo = (const float*)d_in[7];
  float* out = (float*)d_out;

  char* ws = (char*)d_ws;
  u16* xb    = (u16*)(ws + 0);            // 4096x2048 bf16
  u16* wacat = (u16*)(ws + 16777216);     // 1664x2048 bf16
  u16* wqb   = (u16*)(ws + 23592960);     // 3072x1024 bf16
  u16* wkvb  = (u16*)(ws + 29884416);     // 1024x512 bf16
  u16* wo    = (u16*)(ws + 30932992);     // 2048x2048 bf16
  u16* c1b   = (u16*)(ws + 39321600);     // 4096x1664 bf16
  u16* qlat  = (u16*)(ws + 52953088);     // 4096x1024 bf16
  u16* kvlat = (u16*)(ws + 61341696);     // 4096x512 bf16
  u16* obf   = (u16*)(ws + 65536000);     // 4096x2048 bf16
  u16* qattn = (u16*)(ws + 82313216);     // 2x16x2048x192
  u16* kattn = (u16*)(ws + 107479040);    // 2x4x2048x192
  u16* vt    = (u16*)(ws + 113770496);    // 2x4x128x2048
  if (ws_size < 117964800u) return;

  cvt_all<<<19200, 256, 0, stream>>>(x, Wqa, Wkva, Wqb, Wkvb, Wo,
                                     xb, wacat, wqb, wkvb, wo);

  gemm_bt<u16, 1><<<416, 256, 0, stream>>>(xb, wacat, c1b, 4096, 1664, 2048, 13,
                                           nullptr, nullptr, nullptr);
  rms_fused<<<4096, 256, 0, stream>>>(c1b, fc, fs, qlat, kvlat, kattn);
  gemm_bt<u16, 2><<<768, 256, 0, stream>>>(qlat, wqb, qattn, 4096, 3072, 1024, 24,
                                           fc, fs, nullptr);
  gemm_bt<u16, 3><<<256, 256, 0, stream>>>(kvlat, wkvb, kattn, 4096, 1024, 512, 8,
                                           nullptr, nullptr, vt);
  attn_kernel<<<512, 256, 0, stream>>>(qattn, kattn, vt, obf);
  gemm_bt<float, 0><<<512, 256, 0, stream>>>(obf, wo, out, 4096, 2048, 2048, 16,
                                             nullptr, nullptr, nullptr);
}

// Round 13
// 228.536 us; speedup vs baseline: 1.0809x; 1.0398x over previous
//
#include <hip/hip_runtime.h>
#include <cstdint>
#include <cstddef>

typedef __attribute__((ext_vector_type(4))) float f32x4;
typedef __attribute__((ext_vector_type(2))) float f32x2;
typedef __attribute__((ext_vector_type(8))) short short8;
typedef __attribute__((ext_vector_type(8))) __bf16 bf16x8;
typedef unsigned short u16;
typedef unsigned int u32;
typedef __attribute__((ext_vector_type(2))) unsigned int u32x2;
typedef __attribute__((ext_vector_type(4))) unsigned short u16x4;
typedef __attribute__((ext_vector_type(2))) unsigned short u16x2;

#define EPS_RMS 1.1920929e-07f

// ---------- helpers ----------
__device__ __forceinline__ u16 f2bf(float f) {
  union { float f; unsigned u; } v; v.f = f;
  unsigned r = v.u + 0x7FFFu + ((v.u >> 16) & 1u);
  return (u16)(r >> 16);
}
__device__ __forceinline__ float b2f(u16 x) {
  union { unsigned u; float f; } v; v.u = ((unsigned)x) << 16;
  return v.f;
}
__device__ __forceinline__ u32 cvt_pk_bf16(float lo, float hi) {
  u32 r;
  asm("v_cvt_pk_bf16_f32 %0, %1, %2" : "=v"(r) : "v"(lo), "v"(hi));
  return r;
}

template <typename V>
__device__ __forceinline__ auto mfma_try(V a, V b, f32x4 c, int)
    -> decltype(__builtin_amdgcn_mfma_f32_16x16x32_bf16(a, b, c, 0, 0, 0)) {
  return __builtin_amdgcn_mfma_f32_16x16x32_bf16(a, b, c, 0, 0, 0);
}
template <typename V>
__device__ __forceinline__ f32x4 mfma_try(V a, V b, f32x4 c, long) {
  return __builtin_amdgcn_mfma_f32_16x16x32_bf16(
      __builtin_bit_cast(bf16x8, a), __builtin_bit_cast(bf16x8, b), c, 0, 0, 0);
}
__device__ __forceinline__ f32x4 mfma_bf16(short8 a, short8 b, f32x4 c) {
  return mfma_try(a, b, c, 0);
}

__device__ __forceinline__ void load_lds16(u16* lds, const u16* g) {
  auto* gp = reinterpret_cast<const __attribute__((address_space(1))) unsigned int*>(
      reinterpret_cast<uintptr_t>(g));
  auto* lp = reinterpret_cast<__attribute__((address_space(3))) unsigned int*>(
      reinterpret_cast<uintptr_t>(lds));
  __builtin_amdgcn_global_load_lds(gp, lp, 16, 0, 0);
}

__device__ __forceinline__ float fast_exp2(float x) {
  return __builtin_amdgcn_exp2f(x);
}

template <int CTRL>
__device__ __forceinline__ float dpp_step(float v) {
  int t = __builtin_amdgcn_update_dpp(0, __builtin_bit_cast(int, v), CTRL, 0xF, 0xF, true);
  return __builtin_bit_cast(float, t);
}

// ---------- fused conversion kernel (one dispatch for all 5 inputs) ----------
__global__ __launch_bounds__(256) void cvt_all(const float* __restrict__ x,
                                               const float* __restrict__ Wqa,
                                               const float* __restrict__ Wkva,
                                               const float* __restrict__ Wqb,
                                               const float* __restrict__ Wkvb,
                                               const float* __restrict__ Wo,
                                               u16* __restrict__ xb,
                                               u16* __restrict__ wacat,
                                               u16* __restrict__ wqb,
                                               u16* __restrict__ wkvb,
                                               u16* __restrict__ wo) {
  const int blk = blockIdx.x;
  if (blk >= 8192 && blk < 11520) {
    int i = (blk - 8192) * 256 + threadIdx.x;
    int r = i >> 9;
    int c4 = i & 511;
    f32x4 v = {0.f, 0.f, 0.f, 0.f};
    if (r < 1024) v = ((const f32x4*)Wqa)[r * 512 + c4];
    else if (r < 1600) v = ((const f32x4*)Wkva)[(r - 1024) * 512 + c4];
    u16x4 o = {f2bf(v.x), f2bf(v.y), f2bf(v.z), f2bf(v.w)};
    ((u16x4*)wacat)[i] = o;
    return;
  }
  const float* src;
  u16* dst;
  int i;
  if (blk < 8192)       { i = blk * 256 + threadIdx.x;           src = x;    dst = xb;   }
  else if (blk < 14592) { i = (blk - 11520) * 256 + threadIdx.x; src = Wqb;  dst = wqb;  }
  else if (blk < 15104) { i = (blk - 14592) * 256 + threadIdx.x; src = Wkvb; dst = wkvb; }
  else                  { i = (blk - 15104) * 256 + threadIdx.x; src = Wo;   dst = wo;   }
  f32x4 v = ((const f32x4*)src)[i];
  u16x4 o = {f2bf(v.x), f2bf(v.y), f2bf(v.z), f2bf(v.w)};
  ((u16x4*)dst)[i] = o;
}

// ---------- GEMM core (proven dbuf 2-phase body): C[M,N] = A[M,K]*B[N,K]^T ----------
// Byte-identical math to the round-0/6 gemm_bt; (bid,nwg) passed so it can run
// as a sub-grid of a merged launch. EPI: 0=f32 out, 1=bf16 out,
// 2=fused Q rope->Qa, 3=fused KV split->Ka/VT.
template <typename OutT, int EPI>
__device__ __forceinline__ void gemm_core(u16 (&As)[2][128 * 64],
                                          u16 (&Bs)[2][128 * 64],
                                          const u16* __restrict__ A,
                                          const u16* __restrict__ B,
                                          OutT* __restrict__ C,
                                          int N, int K, int gx, int nwg, int bid,
                                          const float* __restrict__ fc,
                                          const float* __restrict__ fs,
                                          u16* __restrict__ aux) {
  const int cpx = nwg >> 3;
  const int swz = (bid & 7) * cpx + (bid >> 3);
  const int by = swz / gx, bxx = swz - by * gx;
  const int tid = threadIdx.x;
  const int lane = tid & 63, w = tid >> 6;
  const int wr = w >> 1, wc = w & 1;
  const int l16 = lane & 15, lg = lane >> 4;
  const int row0 = by * 128, col0 = bxx * 128;

  const u16* Ab = A + (size_t)row0 * K;
  const u16* Bb = B + (size_t)col0 * K;

  f32x4 acc[4][4] = {};

  int soff[4], ldst[4];
#pragma unroll
  for (int j = 0; j < 4; ++j) {
    int c = j * 256 + tid;
    int row = c >> 3;
    int rb = (c & 7) << 4;
    int sb = rb ^ ((row & 7) << 4);
    soff[j] = row * K + (sb >> 1);
    ldst[j] = c * 8;
  }

  // prologue: stage tile 0 into buffer 0
#pragma unroll
  for (int j = 0; j < 4; ++j) load_lds16(As[0] + ldst[j], Ab + soff[j]);
#pragma unroll
  for (int j = 0; j < 4; ++j) load_lds16(Bs[0] + ldst[j], Bb + soff[j]);
  __syncthreads();

  int cur = 0;
  for (int k0 = 0; k0 < K; k0 += 64) {
    if (k0 + 64 < K) {
#pragma unroll
      for (int j = 0; j < 4; ++j) load_lds16(As[cur ^ 1] + ldst[j], Ab + soff[j] + k0 + 64);
#pragma unroll
      for (int j = 0; j < 4; ++j) load_lds16(Bs[cur ^ 1] + ldst[j], Bb + soff[j] + k0 + 64);
    }
    const u16* Ac = As[cur];
    const u16* Bc = Bs[cur];
    short8 a[2][4], bfr[2][4];
#pragma unroll
    for (int mt = 0; mt < 4; ++mt) {
      const int rowA = wr * 64 + mt * 16 + l16;
      const int sw = (rowA & 7) << 4;
#pragma unroll
      for (int kk = 0; kk < 2; ++kk)
        a[kk][mt] = *(const short8*)(Ac + rowA * 64 + (((kk * 64 + lg * 16) ^ sw) >> 1));
    }
#pragma unroll
    for (int nt = 0; nt < 4; ++nt) {
      const int rowB = wc * 64 + nt * 16 + l16;
      const int sw = (rowB & 7) << 4;
#pragma unroll
      for (int kk = 0; kk < 2; ++kk)
        bfr[kk][nt] = *(const short8*)(Bc + rowB * 64 + (((kk * 64 + lg * 16) ^ sw) >> 1));
    }
#pragma unroll
    for (int kk = 0; kk < 2; ++kk)
#pragma unroll
      for (int mt = 0; mt < 4; ++mt)
#pragma unroll
        for (int nt = 0; nt < 4; ++nt)
          acc[mt][nt] = mfma_bf16(a[kk][mt], bfr[kk][nt], acc[mt][nt]);
    __syncthreads();
    cur ^= 1;
  }

  if constexpr (EPI == 0 || EPI == 1) {
#pragma unroll
    for (int mt = 0; mt < 4; ++mt)
#pragma unroll
      for (int nt = 0; nt < 4; ++nt)
#pragma unroll
        for (int i = 0; i < 4; ++i) {
          int row = row0 + wr * 64 + mt * 16 + lg * 4 + i;
          int col = col0 + wc * 64 + nt * 16 + l16;
          if constexpr (EPI == 0)
            C[(size_t)row * N + col] = acc[mt][nt][i];
          else
            C[(size_t)row * N + col] = f2bf(acc[mt][nt][i]);
        }
  } else if constexpr (EPI == 2) {
    const float qscale = 0.07216878364870322f * 1.4426950408889634f;
#pragma unroll
    for (int mt = 0; mt < 4; ++mt)
#pragma unroll
      for (int nt = 0; nt < 4; ++nt) {
        int col = col0 + wc * 64 + nt * 16 + l16;
        int hh = ((col >> 6) * 43) >> 7;   // col/192
        int cin = col - hh * 192;
        int m = (cin - 128) >> 1;
#pragma unroll
        for (int i = 0; i < 4; ++i) {
          int row = row0 + wr * 64 + mt * 16 + lg * 4 + i;
          int bb = row >> 11, ss = row & 2047;
          float v = acc[mt][nt][i];
          float pv = dpp_step<0xB1>(v);  // pair partner (l16^1)
          float val = v;
          if (cin >= 128) {
            float c = fc[ss * 32 + m], sn = fs[ss * 32 + m];
            val = ((l16 & 1) == 0) ? (v * c - pv * sn) : (pv * sn + v * c);
          }
          ((u16*)C)[((size_t)((bb * 16 + hh) * 2048 + ss)) * 192 + cin] = f2bf(val * qscale);
        }
      }
  } else {
#pragma unroll
    for (int mt = 0; mt < 4; ++mt)
#pragma unroll
      for (int nt = 0; nt < 4; ++nt) {
        int col = col0 + wc * 64 + nt * 16 + l16;
        int nn = col >> 8, cin = col & 255;
        int rowb = row0 + wr * 64 + mt * 16 + lg * 4;
        int bb = rowb >> 11, ss0 = rowb & 2047;
        if (cin < 128) {
#pragma unroll
          for (int i = 0; i < 4; ++i)
            ((u16*)C)[((size_t)((bb * 4 + nn) * 2048 + ss0 + i)) * 192 + cin] =
                f2bf(acc[mt][nt][i]);
        } else {
          int dv = cin - 128;
          u16x4 o = {f2bf(acc[mt][nt][0]), f2bf(acc[mt][nt][1]),
                     f2bf(acc[mt][nt][2]), f2bf(acc[mt][nt][3])};
          *(u16x4*)(aux + ((size_t)((bb * 4 + nn) * 128 + dv)) * 2048 + ss0) = o;
        }
      }
  }
}

// ---------- standalone GEMM kernel (G1, G5) ----------
template <typename OutT, int EPI>
__global__ __launch_bounds__(256) void gemm_bt(const u16* __restrict__ A,
                                               const u16* __restrict__ B,
                                               OutT* __restrict__ C,
                                               int N, int K, int gx,
                                               const float* __restrict__ fc,
                                               const float* __restrict__ fs,
                                               u16* __restrict__ aux) {
  __shared__ __align__(16) u16 As[2][128 * 64];
  __shared__ __align__(16) u16 Bs[2][128 * 64];
  gemm_core<OutT, EPI>(As, Bs, A, B, C, N, K, gx, gridDim.x, blockIdx.x,
                       fc, fs, aux);
}

// ---------- merged G2+G3 launch (independent GEMMs, one dispatch) ----------
// blocks [0,768): Q up-proj + rope (EPI=2, N=3072, K=1024)
// blocks [768,1024): KV up-proj + split (EPI=3, N=1024, K=512)
// 1024 blocks = exactly 2 full scheduling waves at 2 blocks/CU: G3's short
// blocks backfill G2's 256-block tail instead of running at half fill after a
// serialized launch. Both sub-grids are %8==0 so the XCD swizzle phase holds.
__global__ __launch_bounds__(256) void gemm_g23(const u16* __restrict__ qlat,
                                                const u16* __restrict__ wqb,
                                                u16* __restrict__ qattn,
                                                const u16* __restrict__ kvlat,
                                                const u16* __restrict__ wkvb,
                                                u16* __restrict__ kattn,
                                                u16* __restrict__ vt,
                                                const float* __restrict__ fc,
                                                const float* __restrict__ fs) {
  __shared__ __align__(16) u16 As[2][128 * 64];
  __shared__ __align__(16) u16 Bs[2][128 * 64];
  if (blockIdx.x < 768) {
    gemm_core<u16, 2>(As, Bs, qlat, wqb, qattn, 3072, 1024, 24, 768,
                      blockIdx.x, fc, fs, nullptr);
  } else {
    gemm_core<u16, 3>(As, Bs, kvlat, wkvb, kattn, 1024, 512, 8, 256,
                      blockIdx.x - 768, nullptr, nullptr, vt);
  }
}

// ---------- fused RMS norms (bf16 input; writes k-rope cols of Ka directly) ----------
__global__ __launch_bounds__(256) void rms_fused(const u16* __restrict__ c1b,
                                                 const float* __restrict__ fc,
                                                 const float* __restrict__ fs,
                                                 u16* __restrict__ qlat,
                                                 u16* __restrict__ kvlat,
                                                 u16* __restrict__ Ka) {
  __shared__ float smq[4], smk[4];
  int t = blockIdx.x;
  const u16* row = c1b + (size_t)t * 1664;
  u16x4 v4u = ((const u16x4*)row)[threadIdx.x];
  u16x2 v2u = ((const u16x2*)(row + 1024))[threadIdx.x];
  float v4x = b2f(v4u.x), v4y = b2f(v4u.y), v4z = b2f(v4u.z), v4w = b2f(v4u.w);
  float v2x = b2f(v2u.x), v2y = b2f(v2u.y);
  float sq = v4x * v4x + v4y * v4y + v4z * v4z + v4w * v4w;
  float sk = v2x * v2x + v2y * v2y;
#pragma unroll
  for (int off = 32; off; off >>= 1) { sq += __shfl_xor(sq, off); sk += __shfl_xor(sk, off); }
  if ((threadIdx.x & 63) == 0) { smq[threadIdx.x >> 6] = sq; smk[threadIdx.x >> 6] = sk; }
  __syncthreads();
  float rq = rsqrtf((smq[0] + smq[1] + smq[2] + smq[3]) * (1.0f / 1024.0f) + EPS_RMS);
  float rk = rsqrtf((smk[0] + smk[1] + smk[2] + smk[3]) * (1.0f / 512.0f) + EPS_RMS);
  u16x4 oq = {f2bf(v4x * rq), f2bf(v4y * rq), f2bf(v4z * rq), f2bf(v4w * rq)};
  ((u16x4*)(qlat + (size_t)t * 1024))[threadIdx.x] = oq;
  u16x2 ok = {f2bf(v2x * rk), f2bf(v2y * rk)};
  ((u16x2*)(kvlat + (size_t)t * 512))[threadIdx.x] = ok;
  if (threadIdx.x < 32) {
    int bb = t >> 11, s = t & 2047;
    int m = threadIdx.x;
    float x0 = b2f(row[1536 + 2 * m]), x1 = b2f(row[1537 + 2 * m]);
    float c = fc[s * 32 + m], sn = fs[s * 32 + m];
    u16 r0 = f2bf(x0 * c - x1 * sn);
    u16 r1 = f2bf(x0 * sn + x1 * c);
#pragma unroll
    for (int nn = 0; nn < 4; ++nn) {
      size_t base = ((size_t)((bb * 4 + nn) * 2048 + s)) * 192 + 128;
      Ka[base + 2 * m] = r0;
      Ka[base + 2 * m + 1] = r1;
    }
  }
}

// ---------- flash attention v10 (proven best: 80.2 us, 2 blocks/CU) ----------
__global__ __launch_bounds__(256, 2) void attn_kernel(const u16* __restrict__ Qa,
                                                      const u16* __restrict__ Ka,
                                                      const u16* __restrict__ VTp,
                                                      u16* __restrict__ Ob) {
  __shared__ __align__(16) u16 Ks[64 * 192];
  __shared__ __align__(16) u16 Vs[128 * 64];
  __shared__ __align__(16) u32 Ppk[4][32][36];
  const int gid = blockIdx.x;
  const int bx = (gid < 256) ? (15 - (gid >> 5)) : ((gid - 256) >> 5);
  const int hb = gid & 31;
  const int b = hb >> 4;
  const int h = hb & 15;
  const int n = h >> 2;
  const int tid = threadIdx.x;
  const int lane = tid & 63;
  const int w = tid >> 6;
  const int l16 = lane & 15;
  const int lg = lane >> 4;

  const u16* Qp = Qa + ((size_t)((b * 16 + h) * 2048 + bx * 128 + w * 32)) * 192;
  const u16* Kp = Ka + ((size_t)((b * 4 + n) * 2048)) * 192;
  const u16* Vp = VTp + ((size_t)((b * 4 + n) * 128)) * 2048;

  int oK[6];
#pragma unroll
  for (int j = 0; j < 6; ++j) {
    int c = j * 256 + tid;
    int row = (c * 2731) >> 16;
    int rb = (c - row * 24) << 4;
    int sb = rb ^ ((row & 7) << 4);
    oK[j] = row * 192 + (sb >> 1);
  }
  int oV[4];
#pragma unroll
  for (int j = 0; j < 4; ++j) {
    int c = j * 256 + tid;
    int row = c >> 3;
    int rb = (c & 7) << 4;
    int sb = rb ^ ((row & 7) << 4);
    oV[j] = row * 2048 + (sb >> 1);
  }

  short8 qf[2][6];
#pragma unroll
  for (int g = 0; g < 2; ++g)
#pragma unroll
    for (int kc = 0; kc < 6; ++kc)
      qf[g][kc] = *(const short8*)(Qp + (size_t)(g * 16 + l16) * 192 + kc * 32 + lg * 8);

  float mrow[2], lrow[2];
  f32x4 oacc[2][8];
#pragma unroll
  for (int g = 0; g < 2; ++g) { mrow[g] = -1e30f; lrow[g] = 0.f; }
#pragma unroll
  for (int g = 0; g < 2; ++g)
#pragma unroll
    for (int vb = 0; vb < 8; ++vb) oacc[g][vb] = (f32x4){0.f, 0.f, 0.f, 0.f};

  const int wrow = bx * 128 + w * 32;
  const int NT = 2 * bx + 2;

  f32x4 kreg[6], vreg[4];
#pragma unroll
  for (int j = 0; j < 6; ++j) kreg[j] = *(const f32x4*)(Kp + oK[j]);
#pragma unroll
  for (int j = 0; j < 4; ++j) vreg[j] = *(const f32x4*)(Vp + oV[j]);

  for (int kt = 0; kt < NT; ++kt) {
    const int kb = kt * 64;
    __syncthreads();
#pragma unroll
    for (int j = 0; j < 6; ++j) *(f32x4*)(Ks + (j * 256 + tid) * 8) = kreg[j];
#pragma unroll
    for (int j = 0; j < 4; ++j) *(f32x4*)(Vs + (j * 256 + tid) * 8) = vreg[j];
    __syncthreads();
    if (kt + 1 < NT) {
      const int kb2 = kb + 64;
#pragma unroll
      for (int j = 0; j < 6; ++j)
        kreg[j] = *(const f32x4*)(Kp + oK[j] + (size_t)kb2 * 192);
#pragma unroll
      for (int j = 0; j < 4; ++j)
        vreg[j] = *(const f32x4*)(Vp + oV[j] + kb2);
    }
    if (kb > wrow + 31) continue;

    f32x4 sc[2][4];
#pragma unroll
    for (int g = 0; g < 2; ++g)
#pragma unroll
      for (int kn = 0; kn < 4; ++kn) sc[g][kn] = (f32x4){0.f, 0.f, 0.f, 0.f};
    __builtin_amdgcn_s_setprio(1);
#pragma unroll
    for (int kn = 0; kn < 4; ++kn) {
      const int rk = kn * 16 + l16;
      const u16* kbase = Ks + rk * 192;
      const int sw = (rk & 7) << 4;
#pragma unroll
      for (int kc = 0; kc < 6; ++kc) {
        short8 kf = *(const short8*)(kbase + (((kc * 64 + lg * 16) ^ sw) >> 1));
        sc[0][kn] = mfma_bf16(kf, qf[0][kc], sc[0][kn]);
        sc[1][kn] = mfma_bf16(kf, qf[1][kc], sc[1][kn]);
      }
    }
    __builtin_amdgcn_s_setprio(0);
    if (kb + 63 > wrow) {
#pragma unroll
      for (int g = 0; g < 2; ++g) {
        const int qabs = wrow + g * 16 + l16;
#pragma unroll
        for (int kn = 0; kn < 4; ++kn)
#pragma unroll
          for (int i = 0; i < 4; ++i)
            if (kb + kn * 16 + lg * 4 + i > qabs) sc[g][kn][i] = -1e30f;
      }
    }
    float pmax[2];
    int need = 0;
#pragma unroll
    for (int g = 0; g < 2; ++g) {
      float v = -1e30f;
#pragma unroll
      for (int kn = 0; kn < 4; ++kn)
        v = fmaxf(v, fmaxf(fmaxf(sc[g][kn][0], sc[g][kn][1]),
                           fmaxf(sc[g][kn][2], sc[g][kn][3])));
      v = fmaxf(v, __shfl_xor(v, 16));
      v = fmaxf(v, __shfl_xor(v, 32));
      pmax[g] = v;
      need |= (v > mrow[g] + 8.0f) ? 1 : 0;
    }
    if (__any(need)) {
#pragma unroll
      for (int g = 0; g < 2; ++g) {
        float mn = fmaxf(mrow[g], pmax[g]);
        float al = fast_exp2(mrow[g] - mn);
        mrow[g] = mn;
        lrow[g] *= al;
#pragma unroll
        for (int i = 0; i < 4; ++i) {
          float alq = __shfl(al, lg * 4 + i);
#pragma unroll
          for (int vb = 0; vb < 8; ++vb) oacc[g][vb][i] *= alq;
        }
      }
    }
#pragma unroll
    for (int g = 0; g < 2; ++g) {
      float rs = 0.f;
#pragma unroll
      for (int kn = 0; kn < 4; ++kn)
#pragma unroll
        for (int i = 0; i < 4; ++i) {
          float p = fast_exp2(sc[g][kn][i] - mrow[g]);
          sc[g][kn][i] = p;
          rs += p;
        }
      rs += __shfl_xor(rs, 16);
      rs += __shfl_xor(rs, 32);
      lrow[g] += rs;
    }
#pragma unroll
    for (int g = 0; g < 2; ++g) {
      const int r = g * 16 + l16;
#pragma unroll
      for (int kn = 0; kn < 4; ++kn) {
        u32x2 pk = {cvt_pk_bf16(sc[g][kn][0], sc[g][kn][1]),
                    cvt_pk_bf16(sc[g][kn][2], sc[g][kn][3])};
        *(u32x2*)&Ppk[w][r][kn * 8 + 2 * lg] = pk;
      }
    }
    short8 pa[2][2];
#pragma unroll
    for (int g = 0; g < 2; ++g) {
      const int r = g * 16 + l16;
      pa[g][0] = *(const short8*)&Ppk[w][r][lg * 4];
      pa[g][1] = *(const short8*)&Ppk[w][r][16 + lg * 4];
    }
    __builtin_amdgcn_s_setprio(1);
#pragma unroll
    for (int vb = 0; vb < 8; ++vb) {
      const int rv = vb * 16 + l16;
      const u16* vbase = Vs + rv * 64;
      const int swv = (rv & 7) << 4;
      short8 v0 = *(const short8*)(vbase + (((lg * 16) ^ swv) >> 1));
      short8 v1 = *(const short8*)(vbase + (((64 + lg * 16) ^ swv) >> 1));
      oacc[0][vb] = mfma_bf16(pa[0][0], v0, oacc[0][vb]);
      oacc[1][vb] = mfma_bf16(pa[1][0], v0, oacc[1][vb]);
      oacc[0][vb] = mfma_bf16(pa[0][1], v1, oacc[0][vb]);
      oacc[1][vb] = mfma_bf16(pa[1][1], v1, oacc[1][vb]);
    }
    __builtin_amdgcn_s_setprio(0);
  }
#pragma unroll
  for (int g = 0; g < 2; ++g) {
    float inv = 1.0f / lrow[g];
#pragma unroll
    for (int i = 0; i < 4; ++i) {
      float invq = __shfl(inv, lg * 4 + i);
      int srow = wrow + g * 16 + lg * 4 + i;
      size_t base = ((size_t)(b * 2048 + srow)) * 2048 + h * 128;
#pragma unroll
      for (int vb = 0; vb < 8; ++vb)
        Ob[base + vb * 16 + l16] = f2bf(oacc[g][vb][i] * invq);
    }
  }
}

// ---------- launch ----------
extern "C" void kernel_launch(void* const* d_in, const int* in_sizes, int n_in,
                              void* d_out, int out_size, void* d_ws, size_t ws_size,
                              hipStream_t stream) {
  const float* x = (const float*)d_in[0];
  const float* fc = (const float*)d_in[1];
  const float* fs = (const float*)d_in[2];
  const float* Wqa = (const float*)d_in[3];
  const float* Wqb = (const float*)d_in[4];
  const float* Wkva = (const float*)d_in[5];
  const float* Wkvb = (const float*)d_in[6];
  const float* Wo = (const float*)d_in[7];
  float* out = (float*)d_out;

  char* ws = (char*)d_ws;
  u16* xb    = (u16*)(ws + 0);            // 4096x2048 bf16
  u16* wacat = (u16*)(ws + 16777216);     // 1664x2048 bf16
  u16* wqb   = (u16*)(ws + 23592960);     // 3072x1024 bf16
  u16* wkvb  = (u16*)(ws + 29884416);     // 1024x512 bf16
  u16* wo    = (u16*)(ws + 30932992);     // 2048x2048 bf16
  u16* c1b   = (u16*)(ws + 39321600);     // 4096x1664 bf16
  u16* qlat  = (u16*)(ws + 52953088);     // 4096x1024 bf16
  u16* kvlat = (u16*)(ws + 61341696);     // 4096x512 bf16
  u16* obf   = (u16*)(ws + 65536000);     // 4096x2048 bf16
  u16* qattn = (u16*)(ws + 82313216);     // 2x16x2048x192
  u16* kattn = (u16*)(ws + 107479040);    // 2x4x2048x192
  u16* vt    = (u16*)(ws + 113770496);    // 2x4x128x2048
  if (ws_size < 117964800u) return;

  cvt_all<<<19200, 256, 0, stream>>>(x, Wqa, Wkva, Wqb, Wkvb, Wo,
                                     xb, wacat, wqb, wkvb, wo);

  gemm_bt<u16, 1><<<416, 256, 0, stream>>>(xb, wacat, c1b, 1664, 2048, 13,
                                           nullptr, nullptr, nullptr);
  rms_fused<<<4096, 256, 0, stream>>>(c1b, fc, fs, qlat, kvlat, kattn);
  gemm_g23<<<1024, 256, 0, stream>>>(qlat, wqb, qattn, kvlat, wkvb, kattn, vt,
                                     fc, fs);
  attn_kernel<<<512, 256, 0, stream>>>(qattn, kattn, vt, obf);
  gemm_bt<float, 0><<<512, 256, 0, stream>>>(obf, wo, out, 2048, 2048, 16,
                                             nullptr, nullptr, nullptr);
}

// Round 14
// 225.667 us; speedup vs baseline: 1.0947x; 1.0127x over previous
//
#include <hip/hip_runtime.h>
#include <cstdint>
#include <cstddef>

typedef __attribute__((ext_vector_type(4))) float f32x4;
typedef __attribute__((ext_vector_type(2))) float f32x2;
typedef __attribute__((ext_vector_type(8))) short short8;
typedef __attribute__((ext_vector_type(8))) __bf16 bf16x8;
typedef unsigned short u16;
typedef unsigned int u32;
typedef __attribute__((ext_vector_type(2))) unsigned int u32x2;
typedef __attribute__((ext_vector_type(4))) unsigned short u16x4;
typedef __attribute__((ext_vector_type(2))) unsigned short u16x2;

#define EPS_RMS 1.1920929e-07f

// ---------- helpers ----------
__device__ __forceinline__ u16 f2bf(float f) {
  union { float f; unsigned u; } v; v.f = f;
  unsigned r = v.u + 0x7FFFu + ((v.u >> 16) & 1u);
  return (u16)(r >> 16);
}
__device__ __forceinline__ float b2f(u16 x) {
  union { unsigned u; float f; } v; v.u = ((unsigned)x) << 16;
  return v.f;
}
__device__ __forceinline__ u32 cvt_pk_bf16(float lo, float hi) {
  u32 r;
  asm("v_cvt_pk_bf16_f32 %0, %1, %2" : "=v"(r) : "v"(lo), "v"(hi));
  return r;
}

template <typename V>
__device__ __forceinline__ auto mfma_try(V a, V b, f32x4 c, int)
    -> decltype(__builtin_amdgcn_mfma_f32_16x16x32_bf16(a, b, c, 0, 0, 0)) {
  return __builtin_amdgcn_mfma_f32_16x16x32_bf16(a, b, c, 0, 0, 0);
}
template <typename V>
__device__ __forceinline__ f32x4 mfma_try(V a, V b, f32x4 c, long) {
  return __builtin_amdgcn_mfma_f32_16x16x32_bf16(
      __builtin_bit_cast(bf16x8, a), __builtin_bit_cast(bf16x8, b), c, 0, 0, 0);
}
__device__ __forceinline__ f32x4 mfma_bf16(short8 a, short8 b, f32x4 c) {
  return mfma_try(a, b, c, 0);
}

__device__ __forceinline__ void load_lds16(u16* lds, const u16* g) {
  auto* gp = reinterpret_cast<const __attribute__((address_space(1))) unsigned int*>(
      reinterpret_cast<uintptr_t>(g));
  auto* lp = reinterpret_cast<__attribute__((address_space(3))) unsigned int*>(
      reinterpret_cast<uintptr_t>(lds));
  __builtin_amdgcn_global_load_lds(gp, lp, 16, 0, 0);
}

__device__ __forceinline__ float fast_exp2(float x) {
  return __builtin_amdgcn_exp2f(x);
}

template <int CTRL>
__device__ __forceinline__ float dpp_step(float v) {
  int t = __builtin_amdgcn_update_dpp(0, __builtin_bit_cast(int, v), CTRL, 0xF, 0xF, true);
  return __builtin_bit_cast(float, t);
}

// ---------- cvt of G1's inputs only (x + wacat); weights deferred to g1w ----------
// [0,8192)      x     -> xb      (2097152 quads)
// [8192,11520)  wacat (Wqa/Wkva concat + zero pad, 851968 quads)
__global__ __launch_bounds__(256) void cvt_xw(const float* __restrict__ x,
                                              const float* __restrict__ Wqa,
                                              const float* __restrict__ Wkva,
                                              u16* __restrict__ xb,
                                              u16* __restrict__ wacat) {
  const int blk = blockIdx.x;
  if (blk < 8192) {
    int i = blk * 256 + threadIdx.x;
    f32x4 v = ((const f32x4*)x)[i];
    u16x4 o = {f2bf(v.x), f2bf(v.y), f2bf(v.z), f2bf(v.w)};
    ((u16x4*)xb)[i] = o;
  } else {
    int i = (blk - 8192) * 256 + threadIdx.x;
    int r = i >> 9;
    int c4 = i & 511;
    f32x4 v = {0.f, 0.f, 0.f, 0.f};
    if (r < 1024) v = ((const f32x4*)Wqa)[r * 512 + c4];
    else if (r < 1600) v = ((const f32x4*)Wkva)[(r - 1024) * 512 + c4];
    u16x4 o = {f2bf(v.x), f2bf(v.y), f2bf(v.z), f2bf(v.w)};
    ((u16x4*)wacat)[i] = o;
  }
}

// ---------- GEMM core (proven dbuf 2-phase body): C[M,N] = A[M,K]*B[N,K]^T ----------
// EPI: 0=f32 out, 1=bf16 out, 2=fused Q rope->Qa, 3=fused KV split->Ka/VT.
template <typename OutT, int EPI>
__device__ __forceinline__ void gemm_core(u16 (&As)[2][128 * 64],
                                          u16 (&Bs)[2][128 * 64],
                                          const u16* __restrict__ A,
                                          const u16* __restrict__ B,
                                          OutT* __restrict__ C,
                                          int N, int K, int gx, int nwg, int bid,
                                          const float* __restrict__ fc,
                                          const float* __restrict__ fs,
                                          u16* __restrict__ aux) {
  const int cpx = nwg >> 3;
  const int swz = (bid & 7) * cpx + (bid >> 3);
  const int by = swz / gx, bxx = swz - by * gx;
  const int tid = threadIdx.x;
  const int lane = tid & 63, w = tid >> 6;
  const int wr = w >> 1, wc = w & 1;
  const int l16 = lane & 15, lg = lane >> 4;
  const int row0 = by * 128, col0 = bxx * 128;

  const u16* Ab = A + (size_t)row0 * K;
  const u16* Bb = B + (size_t)col0 * K;

  f32x4 acc[4][4] = {};

  int soff[4], ldst[4];
#pragma unroll
  for (int j = 0; j < 4; ++j) {
    int c = j * 256 + tid;
    int row = c >> 3;
    int rb = (c & 7) << 4;
    int sb = rb ^ ((row & 7) << 4);
    soff[j] = row * K + (sb >> 1);
    ldst[j] = c * 8;
  }

  // prologue: stage tile 0 into buffer 0
#pragma unroll
  for (int j = 0; j < 4; ++j) load_lds16(As[0] + ldst[j], Ab + soff[j]);
#pragma unroll
  for (int j = 0; j < 4; ++j) load_lds16(Bs[0] + ldst[j], Bb + soff[j]);
  __syncthreads();

  int cur = 0;
  for (int k0 = 0; k0 < K; k0 += 64) {
    if (k0 + 64 < K) {
#pragma unroll
      for (int j = 0; j < 4; ++j) load_lds16(As[cur ^ 1] + ldst[j], Ab + soff[j] + k0 + 64);
#pragma unroll
      for (int j = 0; j < 4; ++j) load_lds16(Bs[cur ^ 1] + ldst[j], Bb + soff[j] + k0 + 64);
    }
    const u16* Ac = As[cur];
    const u16* Bc = Bs[cur];
    short8 a[2][4], bfr[2][4];
#pragma unroll
    for (int mt = 0; mt < 4; ++mt) {
      const int rowA = wr * 64 + mt * 16 + l16;
      const int sw = (rowA & 7) << 4;
#pragma unroll
      for (int kk = 0; kk < 2; ++kk)
        a[kk][mt] = *(const short8*)(Ac + rowA * 64 + (((kk * 64 + lg * 16) ^ sw) >> 1));
    }
#pragma unroll
    for (int nt = 0; nt < 4; ++nt) {
      const int rowB = wc * 64 + nt * 16 + l16;
      const int sw = (rowB & 7) << 4;
#pragma unroll
      for (int kk = 0; kk < 2; ++kk)
        bfr[kk][nt] = *(const short8*)(Bc + rowB * 64 + (((kk * 64 + lg * 16) ^ sw) >> 1));
    }
#pragma unroll
    for (int kk = 0; kk < 2; ++kk)
#pragma unroll
      for (int mt = 0; mt < 4; ++mt)
#pragma unroll
        for (int nt = 0; nt < 4; ++nt)
          acc[mt][nt] = mfma_bf16(a[kk][mt], bfr[kk][nt], acc[mt][nt]);
    __syncthreads();
    cur ^= 1;
  }

  if constexpr (EPI == 0 || EPI == 1) {
#pragma unroll
    for (int mt = 0; mt < 4; ++mt)
#pragma unroll
      for (int nt = 0; nt < 4; ++nt)
#pragma unroll
        for (int i = 0; i < 4; ++i) {
          int row = row0 + wr * 64 + mt * 16 + lg * 4 + i;
          int col = col0 + wc * 64 + nt * 16 + l16;
          if constexpr (EPI == 0)
            C[(size_t)row * N + col] = acc[mt][nt][i];
          else
            C[(size_t)row * N + col] = f2bf(acc[mt][nt][i]);
        }
  } else if constexpr (EPI == 2) {
    const float qscale = 0.07216878364870322f * 1.4426950408889634f;
#pragma unroll
    for (int mt = 0; mt < 4; ++mt)
#pragma unroll
      for (int nt = 0; nt < 4; ++nt) {
        int col = col0 + wc * 64 + nt * 16 + l16;
        int hh = ((col >> 6) * 43) >> 7;   // col/192
        int cin = col - hh * 192;
        int m = (cin - 128) >> 1;
#pragma unroll
        for (int i = 0; i < 4; ++i) {
          int row = row0 + wr * 64 + mt * 16 + lg * 4 + i;
          int bb = row >> 11, ss = row & 2047;
          float v = acc[mt][nt][i];
          float pv = dpp_step<0xB1>(v);  // pair partner (l16^1)
          float val = v;
          if (cin >= 128) {
            float c = fc[ss * 32 + m], sn = fs[ss * 32 + m];
            val = ((l16 & 1) == 0) ? (v * c - pv * sn) : (pv * sn + v * c);
          }
          ((u16*)C)[((size_t)((bb * 16 + hh) * 2048 + ss)) * 192 + cin] = f2bf(val * qscale);
        }
      }
  } else {
#pragma unroll
    for (int mt = 0; mt < 4; ++mt)
#pragma unroll
      for (int nt = 0; nt < 4; ++nt) {
        int col = col0 + wc * 64 + nt * 16 + l16;
        int nn = col >> 8, cin = col & 255;
        int rowb = row0 + wr * 64 + mt * 16 + lg * 4;
        int bb = rowb >> 11, ss0 = rowb & 2047;
        if (cin < 128) {
#pragma unroll
          for (int i = 0; i < 4; ++i)
            ((u16*)C)[((size_t)((bb * 4 + nn) * 2048 + ss0 + i)) * 192 + cin] =
                f2bf(acc[mt][nt][i]);
        } else {
          int dv = cin - 128;
          u16x4 o = {f2bf(acc[mt][nt][0]), f2bf(acc[mt][nt][1]),
                     f2bf(acc[mt][nt][2]), f2bf(acc[mt][nt][3])};
          *(u16x4*)(aux + ((size_t)((bb * 4 + nn) * 128 + dv)) * 2048 + ss0) = o;
        }
      }
  }
}

// ---------- standalone GEMM kernel (G5) ----------
template <typename OutT, int EPI>
__global__ __launch_bounds__(256) void gemm_bt(const u16* __restrict__ A,
                                               const u16* __restrict__ B,
                                               OutT* __restrict__ C,
                                               int N, int K, int gx,
                                               const float* __restrict__ fc,
                                               const float* __restrict__ fs,
                                               u16* __restrict__ aux) {
  __shared__ __align__(16) u16 As[2][128 * 64];
  __shared__ __align__(16) u16 Bs[2][128 * 64];
  gemm_core<OutT, EPI>(As, Bs, A, B, C, N, K, gx, gridDim.x, blockIdx.x,
                       fc, fs, aux);
}

// ---------- merged G1 + weight conversions ----------
// blocks [0,416): G1 GEMM (xb x wacat -> c1b). 416 blocks fill only 81% of
// the 512 slots at 2/CU; the weight conversions (wqb/wkvb/wo, ~47 MB traffic,
// needed only by later dispatches G23/G5) backfill the 48 idle CUs and hide
// under G1's ~43 us. Stream order still sequences them before their readers.
// blocks [416,3488): Wqb -> wqb; [3488,4000): Wkvb -> wkvb; [4000,8096): Wo -> wo.
__global__ __launch_bounds__(256) void gemm_g1w(const u16* __restrict__ xb,
                                                const u16* __restrict__ wacat,
                                                u16* __restrict__ c1b,
                                                const float* __restrict__ Wqb,
                                                const float* __restrict__ Wkvb,
                                                const float* __restrict__ Wo,
                                                u16* __restrict__ wqb,
                                                u16* __restrict__ wkvb,
                                                u16* __restrict__ wo) {
  __shared__ __align__(16) u16 As[2][128 * 64];
  __shared__ __align__(16) u16 Bs[2][128 * 64];
  const int blk = blockIdx.x;
  if (blk < 416) {
    gemm_core<u16, 1>(As, Bs, xb, wacat, c1b, 1664, 2048, 13, 416, blk,
                      nullptr, nullptr, nullptr);
    return;
  }
  const int cb = blk - 416;
  const float* src;
  u16* dst;
  int i;
  if (cb < 3072)      { i = cb * 256 + threadIdx.x;          src = Wqb;  dst = wqb;  }
  else if (cb < 3584) { i = (cb - 3072) * 256 + threadIdx.x; src = Wkvb; dst = wkvb; }
  else                { i = (cb - 3584) * 256 + threadIdx.x; src = Wo;   dst = wo;   }
  f32x4 v = ((const f32x4*)src)[i];
  u16x4 o = {f2bf(v.x), f2bf(v.y), f2bf(v.z), f2bf(v.w)};
  ((u16x4*)dst)[i] = o;
}

// ---------- merged G2+G3 launch (round-13 verified, -9 us) ----------
__global__ __launch_bounds__(256) void gemm_g23(const u16* __restrict__ qlat,
                                                const u16* __restrict__ wqb,
                                                u16* __restrict__ qattn,
                                                const u16* __restrict__ kvlat,
                                                const u16* __restrict__ wkvb,
                                                u16* __restrict__ kattn,
                                                u16* __restrict__ vt,
                                                const float* __restrict__ fc,
                                                const float* __restrict__ fs) {
  __shared__ __align__(16) u16 As[2][128 * 64];
  __shared__ __align__(16) u16 Bs[2][128 * 64];
  if (blockIdx.x < 768) {
    gemm_core<u16, 2>(As, Bs, qlat, wqb, qattn, 3072, 1024, 24, 768,
                      blockIdx.x, fc, fs, nullptr);
  } else {
    gemm_core<u16, 3>(As, Bs, kvlat, wkvb, kattn, 1024, 512, 8, 256,
                      blockIdx.x - 768, nullptr, nullptr, vt);
  }
}

// ---------- fused RMS norms (bf16 input; writes k-rope cols of Ka directly) ----------
__global__ __launch_bounds__(256) void rms_fused(const u16* __restrict__ c1b,
                                                 const float* __restrict__ fc,
                                                 const float* __restrict__ fs,
                                                 u16* __restrict__ qlat,
                                                 u16* __restrict__ kvlat,
                                                 u16* __restrict__ Ka) {
  __shared__ float smq[4], smk[4];
  int t = blockIdx.x;
  const u16* row = c1b + (size_t)t * 1664;
  u16x4 v4u = ((const u16x4*)row)[threadIdx.x];
  u16x2 v2u = ((const u16x2*)(row + 1024))[threadIdx.x];
  float v4x = b2f(v4u.x), v4y = b2f(v4u.y), v4z = b2f(v4u.z), v4w = b2f(v4u.w);
  float v2x = b2f(v2u.x), v2y = b2f(v2u.y);
  float sq = v4x * v4x + v4y * v4y + v4z * v4z + v4w * v4w;
  float sk = v2x * v2x + v2y * v2y;
#pragma unroll
  for (int off = 32; off; off >>= 1) { sq += __shfl_xor(sq, off); sk += __shfl_xor(sk, off); }
  if ((threadIdx.x & 63) == 0) { smq[threadIdx.x >> 6] = sq; smk[threadIdx.x >> 6] = sk; }
  __syncthreads();
  float rq = rsqrtf((smq[0] + smq[1] + smq[2] + smq[3]) * (1.0f / 1024.0f) + EPS_RMS);
  float rk = rsqrtf((smk[0] + smk[1] + smk[2] + smk[3]) * (1.0f / 512.0f) + EPS_RMS);
  u16x4 oq = {f2bf(v4x * rq), f2bf(v4y * rq), f2bf(v4z * rq), f2bf(v4w * rq)};
  ((u16x4*)(qlat + (size_t)t * 1024))[threadIdx.x] = oq;
  u16x2 ok = {f2bf(v2x * rk), f2bf(v2y * rk)};
  ((u16x2*)(kvlat + (size_t)t * 512))[threadIdx.x] = ok;
  if (threadIdx.x < 32) {
    int bb = t >> 11, s = t & 2047;
    int m = threadIdx.x;
    float x0 = b2f(row[1536 + 2 * m]), x1 = b2f(row[1537 + 2 * m]);
    float c = fc[s * 32 + m], sn = fs[s * 32 + m];
    u16 r0 = f2bf(x0 * c - x1 * sn);
    u16 r1 = f2bf(x0 * sn + x1 * c);
#pragma unroll
    for (int nn = 0; nn < 4; ++nn) {
      size_t base = ((size_t)((bb * 4 + nn) * 2048 + s)) * 192 + 128;
      Ka[base + 2 * m] = r0;
      Ka[base + 2 * m + 1] = r1;
    }
  }
}

// ---------- flash attention v10 (proven best: 80.2 us, 2 blocks/CU) ----------
__global__ __launch_bounds__(256, 2) void attn_kernel(const u16* __restrict__ Qa,
                                                      const u16* __restrict__ Ka,
                                                      const u16* __restrict__ VTp,
                                                      u16* __restrict__ Ob) {
  __shared__ __align__(16) u16 Ks[64 * 192];
  __shared__ __align__(16) u16 Vs[128 * 64];
  __shared__ __align__(16) u32 Ppk[4][32][36];
  const int gid = blockIdx.x;
  const int bx = (gid < 256) ? (15 - (gid >> 5)) : ((gid - 256) >> 5);
  const int hb = gid & 31;
  const int b = hb >> 4;
  const int h = hb & 15;
  const int n = h >> 2;
  const int tid = threadIdx.x;
  const int lane = tid & 63;
  const int w = tid >> 6;
  const int l16 = lane & 15;
  const int lg = lane >> 4;

  const u16* Qp = Qa + ((size_t)((b * 16 + h) * 2048 + bx * 128 + w * 32)) * 192;
  const u16* Kp = Ka + ((size_t)((b * 4 + n) * 2048)) * 192;
  const u16* Vp = VTp + ((size_t)((b * 4 + n) * 128)) * 2048;

  int oK[6];
#pragma unroll
  for (int j = 0; j < 6; ++j) {
    int c = j * 256 + tid;
    int row = (c * 2731) >> 16;
    int rb = (c - row * 24) << 4;
    int sb = rb ^ ((row & 7) << 4);
    oK[j] = row * 192 + (sb >> 1);
  }
  int oV[4];
#pragma unroll
  for (int j = 0; j < 4; ++j) {
    int c = j * 256 + tid;
    int row = c >> 3;
    int rb = (c & 7) << 4;
    int sb = rb ^ ((row & 7) << 4);
    oV[j] = row * 2048 + (sb >> 1);
  }

  short8 qf[2][6];
#pragma unroll
  for (int g = 0; g < 2; ++g)
#pragma unroll
    for (int kc = 0; kc < 6; ++kc)
      qf[g][kc] = *(const short8*)(Qp + (size_t)(g * 16 + l16) * 192 + kc * 32 + lg * 8);

  float mrow[2], lrow[2];
  f32x4 oacc[2][8];
#pragma unroll
  for (int g = 0; g < 2; ++g) { mrow[g] = -1e30f; lrow[g] = 0.f; }
#pragma unroll
  for (int g = 0; g < 2; ++g)
#pragma unroll
    for (int vb = 0; vb < 8; ++vb) oacc[g][vb] = (f32x4){0.f, 0.f, 0.f, 0.f};

  const int wrow = bx * 128 + w * 32;
  const int NT = 2 * bx + 2;

  f32x4 kreg[6], vreg[4];
#pragma unroll
  for (int j = 0; j < 6; ++j) kreg[j] = *(const f32x4*)(Kp + oK[j]);
#pragma unroll
  for (int j = 0; j < 4; ++j) vreg[j] = *(const f32x4*)(Vp + oV[j]);

  for (int kt = 0; kt < NT; ++kt) {
    const int kb = kt * 64;
    __syncthreads();
#pragma unroll
    for (int j = 0; j < 6; ++j) *(f32x4*)(Ks + (j * 256 + tid) * 8) = kreg[j];
#pragma unroll
    for (int j = 0; j < 4; ++j) *(f32x4*)(Vs + (j * 256 + tid) * 8) = vreg[j];
    __syncthreads();
    if (kt + 1 < NT) {
      const int kb2 = kb + 64;
#pragma unroll
      for (int j = 0; j < 6; ++j)
        kreg[j] = *(const f32x4*)(Kp + oK[j] + (size_t)kb2 * 192);
#pragma unroll
      for (int j = 0; j < 4; ++j)
        vreg[j] = *(const f32x4*)(Vp + oV[j] + kb2);
    }
    if (kb > wrow + 31) continue;

    f32x4 sc[2][4];
#pragma unroll
    for (int g = 0; g < 2; ++g)
#pragma unroll
      for (int kn = 0; kn < 4; ++kn) sc[g][kn] = (f32x4){0.f, 0.f, 0.f, 0.f};
    __builtin_amdgcn_s_setprio(1);
#pragma unroll
    for (int kn = 0; kn < 4; ++kn) {
      const int rk = kn * 16 + l16;
      const u16* kbase = Ks + rk * 192;
      const int sw = (rk & 7) << 4;
#pragma unroll
      for (int kc = 0; kc < 6; ++kc) {
        short8 kf = *(const short8*)(kbase + (((kc * 64 + lg * 16) ^ sw) >> 1));
        sc[0][kn] = mfma_bf16(kf, qf[0][kc], sc[0][kn]);
        sc[1][kn] = mfma_bf16(kf, qf[1][kc], sc[1][kn]);
      }
    }
    __builtin_amdgcn_s_setprio(0);
    if (kb + 63 > wrow) {
#pragma unroll
      for (int g = 0; g < 2; ++g) {
        const int qabs = wrow + g * 16 + l16;
#pragma unroll
        for (int kn = 0; kn < 4; ++kn)
#pragma unroll
          for (int i = 0; i < 4; ++i)
            if (kb + kn * 16 + lg * 4 + i > qabs) sc[g][kn][i] = -1e30f;
      }
    }
    float pmax[2];
    int need = 0;
#pragma unroll
    for (int g = 0; g < 2; ++g) {
      float v = -1e30f;
#pragma unroll
      for (int kn = 0; kn < 4; ++kn)
        v = fmaxf(v, fmaxf(fmaxf(sc[g][kn][0], sc[g][kn][1]),
                           fmaxf(sc[g][kn][2], sc[g][kn][3])));
      v = fmaxf(v, __shfl_xor(v, 16));
      v = fmaxf(v, __shfl_xor(v, 32));
      pmax[g] = v;
      need |= (v > mrow[g] + 8.0f) ? 1 : 0;
    }
    if (__any(need)) {
#pragma unroll
      for (int g = 0; g < 2; ++g) {
        float mn = fmaxf(mrow[g], pmax[g]);
        float al = fast_exp2(mrow[g] - mn);
        mrow[g] = mn;
        lrow[g] *= al;
#pragma unroll
        for (int i = 0; i < 4; ++i) {
          float alq = __shfl(al, lg * 4 + i);
#pragma unroll
          for (int vb = 0; vb < 8; ++vb) oacc[g][vb][i] *= alq;
        }
      }
    }
#pragma unroll
    for (int g = 0; g < 2; ++g) {
      float rs = 0.f;
#pragma unroll
      for (int kn = 0; kn < 4; ++kn)
#pragma unroll
        for (int i = 0; i < 4; ++i) {
          float p = fast_exp2(sc[g][kn][i] - mrow[g]);
          sc[g][kn][i] = p;
          rs += p;
        }
      rs += __shfl_xor(rs, 16);
      rs += __shfl_xor(rs, 32);
      lrow[g] += rs;
    }
#pragma unroll
    for (int g = 0; g < 2; ++g) {
      const int r = g * 16 + l16;
#pragma unroll
      for (int kn = 0; kn < 4; ++kn) {
        u32x2 pk = {cvt_pk_bf16(sc[g][kn][0], sc[g][kn][1]),
                    cvt_pk_bf16(sc[g][kn][2], sc[g][kn][3])};
        *(u32x2*)&Ppk[w][r][kn * 8 + 2 * lg] = pk;
      }
    }
    short8 pa[2][2];
#pragma unroll
    for (int g = 0; g < 2; ++g) {
      const int r = g * 16 + l16;
      pa[g][0] = *(const short8*)&Ppk[w][r][lg * 4];
      pa[g][1] = *(const short8*)&Ppk[w][r][16 + lg * 4];
    }
    __builtin_amdgcn_s_setprio(1);
#pragma unroll
    for (int vb = 0; vb < 8; ++vb) {
      const int rv = vb * 16 + l16;
      const u16* vbase = Vs + rv * 64;
      const int swv = (rv & 7) << 4;
      short8 v0 = *(const short8*)(vbase + (((lg * 16) ^ swv) >> 1));
      short8 v1 = *(const short8*)(vbase + (((64 + lg * 16) ^ swv) >> 1));
      oacc[0][vb] = mfma_bf16(pa[0][0], v0, oacc[0][vb]);
      oacc[1][vb] = mfma_bf16(pa[1][0], v0, oacc[1][vb]);
      oacc[0][vb] = mfma_bf16(pa[0][1], v1, oacc[0][vb]);
      oacc[1][vb] = mfma_bf16(pa[1][1], v1, oacc[1][vb]);
    }
    __builtin_amdgcn_s_setprio(0);
  }
#pragma unroll
  for (int g = 0; g < 2; ++g) {
    float inv = 1.0f / lrow[g];
#pragma unroll
    for (int i = 0; i < 4; ++i) {
      float invq = __shfl(inv, lg * 4 + i);
      int srow = wrow + g * 16 + lg * 4 + i;
      size_t base = ((size_t)(b * 2048 + srow)) * 2048 + h * 128;
#pragma unroll
      for (int vb = 0; vb < 8; ++vb)
        Ob[base + vb * 16 + l16] = f2bf(oacc[g][vb][i] * invq);
    }
  }
}

// ---------- launch ----------
extern "C" void kernel_launch(void* const* d_in, const int* in_sizes, int n_in,
                              void* d_out, int out_size, void* d_ws, size_t ws_size,
                              hipStream_t stream) {
  const float* x = (const float*)d_in[0];
  const float* fc = (const float*)d_in[1];
  const float* fs = (const float*)d_in[2];
  const float* Wqa = (const float*)d_in[3];
  const float* Wqb = (const float*)d_in[4];
  const float* Wkva = (const float*)d_in[5];
  const float* Wkvb = (const float*)d_in[6];
  const float* Wo = (const float*)d_in[7];
  float* out = (float*)d_out;

  char* ws = (char*)d_ws;
  u16* xb    = (u16*)(ws + 0);            // 4096x2048 bf16
  u16* wacat = (u16*)(ws + 16777216);     // 1664x2048 bf16
  u16* wqb   = (u16*)(ws + 23592960);     // 3072x1024 bf16
  u16* wkvb  = (u16*)(ws + 29884416);     // 1024x512 bf16
  u16* wo    = (u16*)(ws + 30932992);     // 2048x2048 bf16
  u16* c1b   = (u16*)(ws + 39321600);     // 4096x1664 bf16
  u16* qlat  = (u16*)(ws + 52953088);     // 4096x1024 bf16
  u16* kvlat = (u16*)(ws + 61341696);     // 4096x512 bf16
  u16* obf   = (u16*)(ws + 65536000);     // 4096x2048 bf16
  u16* qattn = (u16*)(ws + 82313216);     // 2x16x2048x192
  u16* kattn = (u16*)(ws + 107479040);    // 2x4x2048x192
  u16* vt    = (u16*)(ws + 113770496);    // 2x4x128x2048
  if (ws_size < 117964800u) return;

  cvt_xw<<<11520, 256, 0, stream>>>(x, Wqa, Wkva, xb, wacat);

  gemm_g1w<<<8096, 256, 0, stream>>>(xb, wacat, c1b, Wqb, Wkvb, Wo,
                                     wqb, wkvb, wo);
  rms_fused<<<4096, 256, 0, stream>>>(c1b, fc, fs, qlat, kvlat, kattn);
  gemm_g23<<<1024, 256, 0, stream>>>(qlat, wqb, qattn, kvlat, wkvb, kattn, vt,
                                     fc, fs);
  attn_kernel<<<512, 256, 0, stream>>>(qattn, kattn, vt, obf);
  gemm_bt<float, 0><<<512, 256, 0, stream>>>(obf, wo, out, 2048, 2048, 16,
                                             nullptr, nullptr, nullptr);
}